// Round 1
// baseline (812.757 us; speedup 1.0000x reference)
//
#include <hip/hip_runtime.h>
#include <math.h>

#define ACT_RELU 0
#define ACT_LSM  1

// ---------------- CSR build ----------------
__global__ void k_hist(const int* __restrict__ dst, int* __restrict__ cnt, int E) {
  int i = blockIdx.x * blockDim.x + threadIdx.x;
  if (i < E) atomicAdd(&cnt[dst[i]], 1);
}

__global__ void k_scan_part(const int* __restrict__ cnt, int* __restrict__ bsum, int M) {
  __shared__ int sm[256];
  int t = threadIdx.x;
  int base = blockIdx.x * 2048 + t * 8;
  int s = 0;
#pragma unroll
  for (int j = 0; j < 8; ++j) { int i = base + j; if (i < M) s += cnt[i]; }
  sm[t] = s;
  __syncthreads();
  for (int off = 128; off > 0; off >>= 1) {
    if (t < off) sm[t] += sm[t + off];
    __syncthreads();
  }
  if (t == 0) bsum[blockIdx.x] = sm[0];
}

__global__ void k_scan_mid(const int* __restrict__ bsum, int* __restrict__ boff, int nb) {
  int l = threadIdx.x;  // 64 threads, nb <= 64
  int v = (l < nb) ? bsum[l] : 0;
  int inc = v;
  for (int off = 1; off < 64; off <<= 1) {
    int u = __shfl_up(inc, off);
    if (l >= off) inc += u;
  }
  if (l < nb) boff[l] = inc - v;
}

__global__ void k_scan_final(const int* __restrict__ cnt, const int* __restrict__ boff,
                             int* __restrict__ row_ptr, int* __restrict__ cursor, int M) {
  __shared__ int sm[256];
  int t = threadIdx.x;
  int base = blockIdx.x * 2048 + t * 8;
  int v[8];
  int s = 0;
#pragma unroll
  for (int j = 0; j < 8; ++j) { int i = base + j; v[j] = (i < M) ? cnt[i] : 0; s += v[j]; }
  sm[t] = s;
  __syncthreads();
  for (int off = 1; off < 256; off <<= 1) {
    int x = (t >= off) ? sm[t - off] : 0;
    __syncthreads();
    sm[t] += x;
    __syncthreads();
  }
  int run = boff[blockIdx.x] + sm[t] - s;  // exclusive prefix of this thread's first elem
#pragma unroll
  for (int j = 0; j < 8; ++j) {
    int i = base + j;
    if (i < M) { row_ptr[i] = run; cursor[i] = run; }
    run += v[j];
  }
}

__global__ void k_fill(const int* __restrict__ src, const int* __restrict__ dst,
                       int* __restrict__ cursor, int* __restrict__ edge_src, int E) {
  int i = blockIdx.x * blockDim.x + threadIdx.x;
  if (i < E) {
    int d = dst[i];
    int p = atomicAdd(&cursor[d], 1);
    edge_src[p] = src[i];
  }
}

// ---------------- dense transform: y = h @ W  (h: n x 64, W: 64 x DOUT) ----------------
template <int DOUT>
__global__ void __launch_bounds__(256) k_transform(const float* __restrict__ h,
                                                   const float* __restrict__ W,
                                                   float* __restrict__ y, int n) {
  __shared__ float Ws[64 * DOUT];
  __shared__ float hs[128 * 65];  // +1 pad: avoids bank conflicts on column reads
  int t = threadIdx.x;
  int nbase = blockIdx.x * 128;
  for (int l = t; l < 64 * DOUT; l += 256) Ws[l] = W[l];
#pragma unroll
  for (int j = 0; j < 32; ++j) {
    int l = t + 256 * j;  // 0..8191
    int r = l >> 6, c = l & 63;
    int gi = nbase + r;
    hs[r * 65 + c] = (gi < n) ? h[gi * 64 + c] : 0.f;
  }
  __syncthreads();
  int dg = t & 7, d0 = dg * 8;  // 8 dim-groups of 8 dims
  int ng = t >> 3;              // 32 node-groups of 4 nodes
  if (d0 < DOUT) {
    float acc[4][8];
#pragma unroll
    for (int j = 0; j < 4; ++j)
#pragma unroll
      for (int c = 0; c < 8; ++c) acc[j][c] = 0.f;
#pragma unroll 4
    for (int k = 0; k < 64; ++k) {
      float4 wa = *(const float4*)&Ws[k * DOUT + d0];
      float4 wb = *(const float4*)&Ws[k * DOUT + d0 + 4];
#pragma unroll
      for (int j = 0; j < 4; ++j) {
        float hv = hs[(ng * 4 + j) * 65 + k];
        acc[j][0] += hv * wa.x; acc[j][1] += hv * wa.y;
        acc[j][2] += hv * wa.z; acc[j][3] += hv * wa.w;
        acc[j][4] += hv * wb.x; acc[j][5] += hv * wb.y;
        acc[j][6] += hv * wb.z; acc[j][7] += hv * wb.w;
      }
    }
#pragma unroll
    for (int j = 0; j < 4; ++j) {
      int gi = nbase + ng * 4 + j;
      if (gi < n) {
        *(float4*)&y[gi * DOUT + d0] =
            make_float4(acc[j][0], acc[j][1], acc[j][2], acc[j][3]);
        *(float4*)&y[gi * DOUT + d0 + 4] =
            make_float4(acc[j][4], acc[j][5], acc[j][6], acc[j][7]);
      }
    }
  }
}

// ---------------- fused aggregate + lin_r + bias + activation ----------------
// out[i] = (sum_{j in N(i)} y[j]) / max(deg,1) + h[i]@Wr + bias, then act.
// One wave per node. Lane layout: g = lane&15 (dim-group of 4), rep = lane>>4
// (4 edge replicas). Edge loads are float4: 4 edges x 16 groups = 1KB/wave-instr.
template <int DOUT, int ACT>
__global__ void __launch_bounds__(256) k_aggregate(const float* __restrict__ y,
                                                   const float* h,  // may alias out
                                                   const float* __restrict__ Wr,
                                                   const float* __restrict__ bias,
                                                   const int* __restrict__ row_ptr,
                                                   const int* __restrict__ edge_src,
                                                   float* out, int n) {
  constexpr int G = DOUT / 4;  // 16 (d=64) or 10 (d=40)
  __shared__ float Wr_s[64 * DOUT];
  int t = threadIdx.x;
  for (int l = t; l < 64 * DOUT; l += 256) Wr_s[l] = Wr[l];
  __syncthreads();
  int i = blockIdx.x * 4 + (t >> 6);
  if (i >= n) return;
  int lane = t & 63;
  int g = lane & 15;
  int rep = lane >> 4;
  int gc = (g < G) ? g : 0;
  bool gv = (g < G);
  int rp0 = row_ptr[i], rp1 = row_ptr[i + 1];
  float a0 = 0.f, a1 = 0.f, a2 = 0.f, a3 = 0.f;

  for (int base = rp0; base < rp1; base += 64) {
    int idx = base + lane;
    int sv = (idx < rp1) ? edge_src[idx] : 0;  // up to 64 srcs, coalesced
    int cnt = min(64, rp1 - base);
    for (int e0 = 0; e0 < cnt; e0 += 16) {
#pragma unroll
      for (int u = 0; u < 4; ++u) {
        int e = e0 + u * 4 + rep;
        int s = __shfl(sv, e);
        if (e < cnt) {
          const float4 v = *(const float4*)&y[s * DOUT + gc * 4];
          a0 += v.x; a1 += v.y; a2 += v.z; a3 += v.w;
        }
      }
    }
  }
  // fold the 4 edge-replicas
  a0 += __shfl_xor(a0, 16); a0 += __shfl_xor(a0, 32);
  a1 += __shfl_xor(a1, 16); a1 += __shfl_xor(a1, 32);
  a2 += __shfl_xor(a2, 16); a2 += __shfl_xor(a2, 32);
  a3 += __shfl_xor(a3, 16); a3 += __shfl_xor(a3, 32);

  int deg = rp1 - rp0;
  float scale = (deg > 0) ? (1.0f / (float)deg) : 0.f;
  a0 *= scale; a1 *= scale; a2 *= scale; a3 *= scale;

  // + h[i] @ Wr (h row broadcast via shuffles; Wr from LDS)
  float hv = h[i * 64 + lane];
#pragma unroll
  for (int k = 0; k < 64; ++k) {
    float hk = __shfl(hv, k);
    const float4 w = *(const float4*)&Wr_s[k * DOUT + gc * 4];
    a0 += hk * w.x; a1 += hk * w.y; a2 += hk * w.z; a3 += hk * w.w;
  }
  const float4 bb = *(const float4*)&bias[gc * 4];
  a0 += bb.x; a1 += bb.y; a2 += bb.z; a3 += bb.w;

  if (ACT == ACT_RELU) {
    if (rep == 0 && gv) {
      *(float4*)&out[i * DOUT + g * 4] =
          make_float4(fmaxf(a0, 0.f), fmaxf(a1, 0.f), fmaxf(a2, 0.f), fmaxf(a3, 0.f));
    }
  } else {
    float m = gv ? fmaxf(fmaxf(a0, a1), fmaxf(a2, a3)) : -INFINITY;
#pragma unroll
    for (int off = 1; off < 16; off <<= 1) m = fmaxf(m, __shfl_xor(m, off));
    float e0 = gv ? expf(a0 - m) : 0.f;
    float e1 = gv ? expf(a1 - m) : 0.f;
    float e2 = gv ? expf(a2 - m) : 0.f;
    float e3 = gv ? expf(a3 - m) : 0.f;
    float es = ((e0 + e1) + (e2 + e3));
#pragma unroll
    for (int off = 1; off < 16; off <<= 1) es += __shfl_xor(es, off);
    float lse = logf(es);
    if (rep == 0 && gv) {
      *(float4*)&out[i * DOUT + g * 4] =
          make_float4(a0 - m - lse, a1 - m - lse, a2 - m - lse, a3 - m - lse);
    }
  }
}

extern "C" void kernel_launch(void* const* d_in, const int* in_sizes, int n_in,
                              void* d_out, int out_size, void* d_ws, size_t ws_size,
                              hipStream_t stream) {
  const float* x   = (const float*)d_in[0];
  const int*   ei  = (const int*)d_in[1];
  const float* Wl0 = (const float*)d_in[2];
  const float* bl0 = (const float*)d_in[3];
  const float* Wr0 = (const float*)d_in[4];
  const float* Wl1 = (const float*)d_in[5];
  const float* bl1 = (const float*)d_in[6];
  const float* Wr1 = (const float*)d_in[7];
  const float* Wl2 = (const float*)d_in[8];
  const float* bl2 = (const float*)d_in[9];
  const float* Wr2 = (const float*)d_in[10];
  float* out = (float*)d_out;

  int N = in_sizes[0] / 64;
  int E = in_sizes[1] / 2;
  int M = N + 1;
  const int* src = ei;
  const int* dst = ei + E;

  char* p = (char*)d_ws;
  auto alloc = [&](size_t bytes) {
    char* r = p;
    p += (bytes + 255) & ~(size_t)255;
    return r;
  };
  int* cnt      = (int*)alloc((size_t)M * 4);
  int* row_ptr  = (int*)alloc((size_t)M * 4);
  int* cursor   = (int*)alloc((size_t)M * 4);
  int* bsum     = (int*)alloc(256 * 4);
  int* boff     = (int*)alloc(256 * 4);
  int* edge_src = (int*)alloc((size_t)E * 4);
  float* A      = (float*)alloc((size_t)N * 64 * 4);  // y (transformed features)
  float* B      = (float*)alloc((size_t)N * 64 * 4);  // hidden states (ping/in-place)
  if ((size_t)(p - (char*)d_ws) > ws_size) return;    // ws too small: fail loudly

  hipMemsetAsync(cnt, 0, (size_t)M * 4, stream);
  int eb = (E + 255) / 256;
  k_hist<<<eb, 256, 0, stream>>>(dst, cnt, E);
  int nb = (M + 2047) / 2048;  // 49 for N=100000 (<=64 required by k_scan_mid)
  k_scan_part<<<nb, 256, 0, stream>>>(cnt, bsum, M);
  k_scan_mid<<<1, 64, 0, stream>>>(bsum, boff, nb);
  k_scan_final<<<nb, 256, 0, stream>>>(cnt, boff, row_ptr, cursor, M);
  k_fill<<<eb, 256, 0, stream>>>(src, dst, cursor, edge_src, E);

  int tb = (N + 127) / 128;
  int ab = (N + 3) / 4;
  // layer 0: h1 = relu(mean_agg(x@Wl0) + x@Wr0 + bl0)
  k_transform<64><<<tb, 256, 0, stream>>>(x, Wl0, A, N);
  k_aggregate<64, ACT_RELU><<<ab, 256, 0, stream>>>(A, x, Wr0, bl0, row_ptr, edge_src, B, N);
  // layer 1: h2 = relu(...)   (in-place over B: each wave touches only its own row)
  k_transform<64><<<tb, 256, 0, stream>>>(B, Wl1, A, N);
  k_aggregate<64, ACT_RELU><<<ab, 256, 0, stream>>>(A, B, Wr1, bl1, row_ptr, edge_src, B, N);
  // layer 2: out = log_softmax(mean_agg(h2@Wl2) + h2@Wr2 + bl2)
  k_transform<40><<<tb, 256, 0, stream>>>(B, Wl2, A, N);
  k_aggregate<40, ACT_LSM><<<ab, 256, 0, stream>>>(A, B, Wr2, bl2, row_ptr, edge_src, out, N);
}

// Round 2
// 541.576 us; speedup vs baseline: 1.5007x; 1.5007x over previous
//
#include <hip/hip_runtime.h>
#include <math.h>

#define ACT_RELU 0
#define ACT_LSM  1

// ---------------- CSR build ----------------
__global__ void k_hist(const int* __restrict__ dst, int* __restrict__ cnt, int E) {
  int i = blockIdx.x * blockDim.x + threadIdx.x;
  if (i < E) atomicAdd(&cnt[dst[i]], 1);
}

__global__ void k_scan_part(const int* __restrict__ cnt, int* __restrict__ bsum, int M) {
  __shared__ int sm[256];
  int t = threadIdx.x;
  int base = blockIdx.x * 2048 + t * 8;
  int s = 0;
#pragma unroll
  for (int j = 0; j < 8; ++j) { int i = base + j; if (i < M) s += cnt[i]; }
  sm[t] = s;
  __syncthreads();
  for (int off = 128; off > 0; off >>= 1) {
    if (t < off) sm[t] += sm[t + off];
    __syncthreads();
  }
  if (t == 0) bsum[blockIdx.x] = sm[0];
}

__global__ void k_scan_mid(const int* __restrict__ bsum, int* __restrict__ boff, int nb) {
  int l = threadIdx.x;  // 64 threads, nb <= 64
  int v = (l < nb) ? bsum[l] : 0;
  int inc = v;
  for (int off = 1; off < 64; off <<= 1) {
    int u = __shfl_up(inc, off);
    if (l >= off) inc += u;
  }
  if (l < nb) boff[l] = inc - v;
}

__global__ void k_scan_final(const int* __restrict__ cnt, const int* __restrict__ boff,
                             int* __restrict__ row_ptr, int* __restrict__ cursor, int M) {
  __shared__ int sm[256];
  int t = threadIdx.x;
  int base = blockIdx.x * 2048 + t * 8;
  int v[8];
  int s = 0;
#pragma unroll
  for (int j = 0; j < 8; ++j) { int i = base + j; v[j] = (i < M) ? cnt[i] : 0; s += v[j]; }
  sm[t] = s;
  __syncthreads();
  for (int off = 1; off < 256; off <<= 1) {
    int x = (t >= off) ? sm[t - off] : 0;
    __syncthreads();
    sm[t] += x;
    __syncthreads();
  }
  int run = boff[blockIdx.x] + sm[t] - s;  // exclusive prefix of this thread's first elem
#pragma unroll
  for (int j = 0; j < 8; ++j) {
    int i = base + j;
    if (i < M) { row_ptr[i] = run; cursor[i] = run; }
    run += v[j];
  }
}

__global__ void k_fill(const int* __restrict__ src, const int* __restrict__ dst,
                       int* __restrict__ cursor, int* __restrict__ edge_src, int E) {
  int i = blockIdx.x * blockDim.x + threadIdx.x;
  if (i < E) {
    int d = dst[i];
    int p = atomicAdd(&cursor[d], 1);
    edge_src[p] = src[i];
  }
}

// ---------------- dense transform: Y = h@Wl ; Z = h@Wr + b ----------------
// Z may be written into the same buffer as h (block stages its own rows into
// LDS before overwriting; GEMM is row-to-row, no cross-row reads).
template <int DOUT>
__global__ void __launch_bounds__(256) k_transform2(const float* __restrict__ h,
                                                    const float* __restrict__ Wl,
                                                    const float* __restrict__ Wr,
                                                    const float* __restrict__ bias,
                                                    float* __restrict__ Y,
                                                    float* Z, int n) {
  __shared__ float Ws[64 * DOUT];
  __shared__ float hs[128 * 65];  // +1 pad: conflict-free column reads
  int t = threadIdx.x;
  int nbase = blockIdx.x * 128;
#pragma unroll
  for (int j = 0; j < 32; ++j) {
    int l = t + 256 * j;  // 0..8191
    int r = l >> 6, c = l & 63;
    int gi = nbase + r;
    hs[r * 65 + c] = (gi < n) ? h[gi * 64 + c] : 0.f;
  }
  int dg = t & 7, d0 = dg * 8;  // 8 dim-groups of 8 dims
  int ng = t >> 3;              // 32 node-groups of 4 nodes

  for (int pass = 0; pass < 2; ++pass) {
    const float* W = pass ? Wr : Wl;
    float* O = pass ? Z : Y;
    __syncthreads();  // pass0: hs ready; pass1: pass0 done reading Ws
    for (int l = t; l < 64 * DOUT; l += 256) Ws[l] = W[l];
    __syncthreads();
    if (d0 < DOUT) {
      float acc[4][8];
#pragma unroll
      for (int j = 0; j < 4; ++j)
#pragma unroll
        for (int c = 0; c < 8; ++c) acc[j][c] = 0.f;
#pragma unroll 4
      for (int k = 0; k < 64; ++k) {
        float4 wa = *(const float4*)&Ws[k * DOUT + d0];
        float4 wb = *(const float4*)&Ws[k * DOUT + d0 + 4];
#pragma unroll
        for (int j = 0; j < 4; ++j) {
          float hv = hs[(ng * 4 + j) * 65 + k];
          acc[j][0] += hv * wa.x; acc[j][1] += hv * wa.y;
          acc[j][2] += hv * wa.z; acc[j][3] += hv * wa.w;
          acc[j][4] += hv * wb.x; acc[j][5] += hv * wb.y;
          acc[j][6] += hv * wb.z; acc[j][7] += hv * wb.w;
        }
      }
      if (pass) {
        float4 ba = *(const float4*)&bias[d0];
        float4 bb = *(const float4*)&bias[d0 + 4];
#pragma unroll
        for (int j = 0; j < 4; ++j) {
          acc[j][0] += ba.x; acc[j][1] += ba.y; acc[j][2] += ba.z; acc[j][3] += ba.w;
          acc[j][4] += bb.x; acc[j][5] += bb.y; acc[j][6] += bb.z; acc[j][7] += bb.w;
        }
      }
#pragma unroll
      for (int j = 0; j < 4; ++j) {
        int gi = nbase + ng * 4 + j;
        if (gi < n) {
          *(float4*)&O[gi * DOUT + d0] =
              make_float4(acc[j][0], acc[j][1], acc[j][2], acc[j][3]);
          *(float4*)&O[gi * DOUT + d0 + 4] =
              make_float4(acc[j][4], acc[j][5], acc[j][6], acc[j][7]);
        }
      }
    }
  }
}

// ---------------- pure aggregate: out[i] = gather_mean(Y) + out[i], act ----------------
// out already holds Z = h@Wr + b (written by k_transform2).
// 4 nodes per wave, 16 lanes per node: per edge-step one 256B row per node,
// 1KB per wave load-instruction, 4 loads in flight per lane.
template <int DOUT, int ACT>
__global__ void __launch_bounds__(256) k_aggregate(const float* __restrict__ y,
                                                   const int* __restrict__ row_ptr,
                                                   const int* __restrict__ edge_src,
                                                   float* out, int n) {
  constexpr int G = DOUT / 4;  // 16 (d=64) or 10 (d=40)
  int t = threadIdx.x;
  int lane = t & 63;
  int sub = lane >> 4;  // node within wave
  int g = lane & 15;    // dim-group of 4
  int i = blockIdx.x * 16 + (t >> 6) * 4 + sub;
  if (i >= n) return;
  bool gv = (g < G);
  int gc = gv ? g : 0;
  int rp0 = row_ptr[i], rp1 = row_ptr[i + 1];
  int deg = rp1 - rp0;
  float a0 = 0.f, a1 = 0.f, a2 = 0.f, a3 = 0.f;

  for (int base = 0; base < deg; base += 16) {
    int sv = (base + g < deg) ? edge_src[rp0 + base + g] : 0;
    int cnt = min(16, deg - base);
    for (int q = 0; q < cnt; q += 4) {
#pragma unroll
      for (int u = 0; u < 4; ++u) {
        int e = q + u;
        int s = __shfl(sv, (sub << 4) | e);
        if (e < cnt) {
          const float4 v = *(const float4*)&y[s * DOUT + gc * 4];
          a0 += v.x; a1 += v.y; a2 += v.z; a3 += v.w;
        }
      }
    }
  }

  float scale = (deg > 0) ? (1.0f / (float)deg) : 0.f;
  a0 *= scale; a1 *= scale; a2 *= scale; a3 *= scale;

  const float4 z = *(const float4*)&out[i * DOUT + gc * 4];  // Z = h@Wr + b
  a0 += z.x; a1 += z.y; a2 += z.z; a3 += z.w;

  if (ACT == ACT_RELU) {
    if (gv) {
      *(float4*)&out[i * DOUT + g * 4] =
          make_float4(fmaxf(a0, 0.f), fmaxf(a1, 0.f), fmaxf(a2, 0.f), fmaxf(a3, 0.f));
    }
  } else {
    float m = gv ? fmaxf(fmaxf(a0, a1), fmaxf(a2, a3)) : -INFINITY;
#pragma unroll
    for (int off = 1; off < 16; off <<= 1) m = fmaxf(m, __shfl_xor(m, off));
    float e0 = gv ? expf(a0 - m) : 0.f;
    float e1 = gv ? expf(a1 - m) : 0.f;
    float e2 = gv ? expf(a2 - m) : 0.f;
    float e3 = gv ? expf(a3 - m) : 0.f;
    float es = ((e0 + e1) + (e2 + e3));
#pragma unroll
    for (int off = 1; off < 16; off <<= 1) es += __shfl_xor(es, off);
    float lse = logf(es);
    if (gv) {
      *(float4*)&out[i * DOUT + g * 4] =
          make_float4(a0 - m - lse, a1 - m - lse, a2 - m - lse, a3 - m - lse);
    }
  }
}

extern "C" void kernel_launch(void* const* d_in, const int* in_sizes, int n_in,
                              void* d_out, int out_size, void* d_ws, size_t ws_size,
                              hipStream_t stream) {
  const float* x   = (const float*)d_in[0];
  const int*   ei  = (const int*)d_in[1];
  const float* Wl0 = (const float*)d_in[2];
  const float* bl0 = (const float*)d_in[3];
  const float* Wr0 = (const float*)d_in[4];
  const float* Wl1 = (const float*)d_in[5];
  const float* bl1 = (const float*)d_in[6];
  const float* Wr1 = (const float*)d_in[7];
  const float* Wl2 = (const float*)d_in[8];
  const float* bl2 = (const float*)d_in[9];
  const float* Wr2 = (const float*)d_in[10];
  float* out = (float*)d_out;

  int N = in_sizes[0] / 64;
  int E = in_sizes[1] / 2;
  int M = N + 1;
  const int* src = ei;
  const int* dst = ei + E;

  char* p = (char*)d_ws;
  auto alloc = [&](size_t bytes) {
    char* r = p;
    p += (bytes + 255) & ~(size_t)255;
    return r;
  };
  int* cnt      = (int*)alloc((size_t)M * 4);
  int* row_ptr  = (int*)alloc((size_t)M * 4);
  int* cursor   = (int*)alloc((size_t)M * 4);
  int* bsum     = (int*)alloc(256 * 4);
  int* boff     = (int*)alloc(256 * 4);
  int* edge_src = (int*)alloc((size_t)E * 4);
  float* A      = (float*)alloc((size_t)N * 64 * 4);  // Y (transformed features)
  float* B      = (float*)alloc((size_t)N * 64 * 4);  // hidden states / Z
  if ((size_t)(p - (char*)d_ws) > ws_size) return;    // ws too small: fail loudly

  hipMemsetAsync(cnt, 0, (size_t)M * 4, stream);
  int eb = (E + 255) / 256;
  k_hist<<<eb, 256, 0, stream>>>(dst, cnt, E);
  int nb = (M + 2047) / 2048;  // 49 for N=100000 (<=64 required by k_scan_mid)
  k_scan_part<<<nb, 256, 0, stream>>>(cnt, bsum, M);
  k_scan_mid<<<1, 64, 0, stream>>>(bsum, boff, nb);
  k_scan_final<<<nb, 256, 0, stream>>>(cnt, boff, row_ptr, cursor, M);
  k_fill<<<eb, 256, 0, stream>>>(src, dst, cursor, edge_src, E);

  int tb = (N + 127) / 128;
  int ab = (N + 15) / 16;
  // layer 0: A = x@Wl0 ; B = x@Wr0 + bl0 ; B = relu(agg(A)/deg + B)
  k_transform2<64><<<tb, 256, 0, stream>>>(x, Wl0, Wr0, bl0, A, B, N);
  k_aggregate<64, ACT_RELU><<<ab, 256, 0, stream>>>(A, row_ptr, edge_src, B, N);
  // layer 1: A = B@Wl1 ; B <- B@Wr1 + bl1 (in-place) ; B = relu(agg(A)/deg + B)
  k_transform2<64><<<tb, 256, 0, stream>>>(B, Wl1, Wr1, bl1, A, B, N);
  k_aggregate<64, ACT_RELU><<<ab, 256, 0, stream>>>(A, row_ptr, edge_src, B, N);
  // layer 2: A = B@Wl2 ; out = B@Wr2 + bl2 ; out = log_softmax(agg(A)/deg + out)
  k_transform2<40><<<tb, 256, 0, stream>>>(B, Wl2, Wr2, bl2, A, out, N);
  k_aggregate<40, ACT_LSM><<<ab, 256, 0, stream>>>(A, row_ptr, edge_src, out, N);
}

// Round 3
// 475.215 us; speedup vs baseline: 1.7103x; 1.1396x over previous
//
#include <hip/hip_runtime.h>
#include <math.h>

#define ACT_RELU 0
#define ACT_LSM  1
#define BSH 8        // bucket = 256 consecutive dst nodes
#define MAXNB 512    // max buckets supported by the scan / LDS hist

// ---------------- CSR build ----------------
// k_hist2: exact per-node histogram (global atomics) + per-bucket histogram
// (LDS-aggregated, one global atomic per bucket per block).
__global__ void k_hist2(const int* __restrict__ dst, int* __restrict__ cnt,
                        int* __restrict__ bucket_cnt, int E, int NB) {
  __shared__ int cntL[MAXNB];
  int t = threadIdx.x;
  for (int b = t; b < NB; b += 256) cntL[b] = 0;
  __syncthreads();
  int e0 = blockIdx.x * 8192;
  int e1 = min(e0 + 8192, E);
  for (int i = e0 + t; i < e1; i += 256) {
    int d = dst[i];
    atomicAdd(&cnt[d], 1);
    atomicAdd(&cntL[d >> BSH], 1);
  }
  __syncthreads();
  for (int b = t; b < NB; b += 256)
    if (cntL[b]) atomicAdd(&bucket_cnt[b], cntL[b]);
}

__global__ void k_scan_part(const int* __restrict__ cnt, int* __restrict__ bsum, int M) {
  __shared__ int sm[256];
  int t = threadIdx.x;
  int base = blockIdx.x * 2048 + t * 8;
  int s = 0;
#pragma unroll
  for (int j = 0; j < 8; ++j) { int i = base + j; if (i < M) s += cnt[i]; }
  sm[t] = s;
  __syncthreads();
  for (int off = 128; off > 0; off >>= 1) {
    if (t < off) sm[t] += sm[t + off];
    __syncthreads();
  }
  if (t == 0) bsum[blockIdx.x] = sm[0];
}

__global__ void k_scan_mid(const int* __restrict__ bsum, int* __restrict__ boff, int nb) {
  int l = threadIdx.x;  // 64 threads, nb <= 64
  int v = (l < nb) ? bsum[l] : 0;
  int inc = v;
  for (int off = 1; off < 64; off <<= 1) {
    int u = __shfl_up(inc, off);
    if (l >= off) inc += u;
  }
  if (l < nb) boff[l] = inc - v;
}

__global__ void k_scan_final(const int* __restrict__ cnt, const int* __restrict__ boff,
                             int* __restrict__ row_ptr, int* __restrict__ cursor, int M) {
  __shared__ int sm[256];
  int t = threadIdx.x;
  int base = blockIdx.x * 2048 + t * 8;
  int v[8];
  int s = 0;
#pragma unroll
  for (int j = 0; j < 8; ++j) { int i = base + j; v[j] = (i < M) ? cnt[i] : 0; s += v[j]; }
  sm[t] = s;
  __syncthreads();
  for (int off = 1; off < 256; off <<= 1) {
    int x = (t >= off) ? sm[t - off] : 0;
    __syncthreads();
    sm[t] += x;
    __syncthreads();
  }
  int run = boff[blockIdx.x] + sm[t] - s;  // exclusive prefix of this thread's first elem
#pragma unroll
  for (int j = 0; j < 8; ++j) {
    int i = base + j;
    if (i < M) { row_ptr[i] = run; cursor[i] = run; }
    run += v[j];
  }
}

// scan of bucket counts (NB <= 512): base (exclusive, +total at [NB]) and cursor
__global__ void k_bscan(const int* __restrict__ bucket_cnt, int* __restrict__ bucket_base,
                        int* __restrict__ bucket_cursor, int NB) {
  __shared__ int sm[MAXNB];
  int t = threadIdx.x;  // 512 threads
  sm[t] = (t < NB) ? bucket_cnt[t] : 0;
  __syncthreads();
  for (int off = 1; off < MAXNB; off <<= 1) {
    int x = (t >= off) ? sm[t - off] : 0;
    __syncthreads();
    sm[t] += x;
    __syncthreads();
  }
  int ex = (t == 0) ? 0 : sm[t - 1];
  if (t <= NB) bucket_base[t] = ex;
  if (t < NB) bucket_cursor[t] = ex;
}

// partition edges into dst-buckets: block reserves a contiguous range per
// bucket (1 global atomic), writes packed (src,dst) nearly line-dense.
__global__ void k_partition(const int* __restrict__ src, const int* __restrict__ dst,
                            int* __restrict__ bucket_cursor, int2* __restrict__ tmp,
                            int E, int NB) {
  __shared__ int cntL[MAXNB];
  __shared__ int baseL[MAXNB];
  int t = threadIdx.x;
  for (int b = t; b < NB; b += 256) cntL[b] = 0;
  __syncthreads();
  int e0 = blockIdx.x * 8192;
  int e1 = min(e0 + 8192, E);
  for (int i = e0 + t; i < e1; i += 256) atomicAdd(&cntL[dst[i] >> BSH], 1);
  __syncthreads();
  for (int b = t; b < NB; b += 256) {
    int c = cntL[b];
    baseL[b] = c ? atomicAdd(&bucket_cursor[b], c) : 0;
    cntL[b] = 0;  // reuse as local cursor
  }
  __syncthreads();
  for (int i = e0 + t; i < e1; i += 256) {
    int s = src[i], d = dst[i];  // second read is L2-hot
    int b = d >> BSH;
    int r = atomicAdd(&cntL[b], 1);
    tmp[baseL[b] + r] = make_int2(s, d);
  }
}

// final CSR fill: one block per bucket; writes span only that bucket's
// ~16KB region of edge_src -> lines fill while resident.
__global__ void k_bfill(const int2* __restrict__ tmp, const int* __restrict__ bucket_base,
                        int* __restrict__ cursor, int* __restrict__ edge_src) {
  int b = blockIdx.x;
  int e0 = bucket_base[b], e1 = bucket_base[b + 1];
  for (int i = e0 + threadIdx.x; i < e1; i += 256) {
    int2 e = tmp[i];
    int p = atomicAdd(&cursor[e.y], 1);
    edge_src[p] = e.x;
  }
}

// fallback (only if NB > MAXNB or tmp doesn't fit): original scatter fill
__global__ void k_fill(const int* __restrict__ src, const int* __restrict__ dst,
                       int* __restrict__ cursor, int* __restrict__ edge_src, int E) {
  int i = blockIdx.x * blockDim.x + threadIdx.x;
  if (i < E) {
    int d = dst[i];
    int p = atomicAdd(&cursor[d], 1);
    edge_src[p] = src[i];
  }
}

// ---------------- dense transform: Y = h@Wl ; Z = h@Wr + b ----------------
// Z may be written into the same buffer as h (block stages its own rows into
// LDS before overwriting; GEMM is row-to-row, no cross-row reads).
template <int DOUT>
__global__ void __launch_bounds__(256) k_transform2(const float* __restrict__ h,
                                                    const float* __restrict__ Wl,
                                                    const float* __restrict__ Wr,
                                                    const float* __restrict__ bias,
                                                    float* __restrict__ Y,
                                                    float* Z, int n) {
  __shared__ float Ws[64 * DOUT];
  __shared__ float hs[128 * 65];  // +1 pad: conflict-free column reads
  int t = threadIdx.x;
  int nbase = blockIdx.x * 128;
#pragma unroll
  for (int j = 0; j < 32; ++j) {
    int l = t + 256 * j;  // 0..8191
    int r = l >> 6, c = l & 63;
    int gi = nbase + r;
    hs[r * 65 + c] = (gi < n) ? h[gi * 64 + c] : 0.f;
  }
  int dg = t & 7, d0 = dg * 8;  // 8 dim-groups of 8 dims
  int ng = t >> 3;              // 32 node-groups of 4 nodes

  for (int pass = 0; pass < 2; ++pass) {
    const float* W = pass ? Wr : Wl;
    float* O = pass ? Z : Y;
    __syncthreads();  // pass0: hs ready; pass1: pass0 done reading Ws
    for (int l = t; l < 64 * DOUT; l += 256) Ws[l] = W[l];
    __syncthreads();
    if (d0 < DOUT) {
      float acc[4][8];
#pragma unroll
      for (int j = 0; j < 4; ++j)
#pragma unroll
        for (int c = 0; c < 8; ++c) acc[j][c] = 0.f;
#pragma unroll 4
      for (int k = 0; k < 64; ++k) {
        float4 wa = *(const float4*)&Ws[k * DOUT + d0];
        float4 wb = *(const float4*)&Ws[k * DOUT + d0 + 4];
#pragma unroll
        for (int j = 0; j < 4; ++j) {
          float hv = hs[(ng * 4 + j) * 65 + k];
          acc[j][0] += hv * wa.x; acc[j][1] += hv * wa.y;
          acc[j][2] += hv * wa.z; acc[j][3] += hv * wa.w;
          acc[j][4] += hv * wb.x; acc[j][5] += hv * wb.y;
          acc[j][6] += hv * wb.z; acc[j][7] += hv * wb.w;
        }
      }
      if (pass) {
        float4 ba = *(const float4*)&bias[d0];
        float4 bb = *(const float4*)&bias[d0 + 4];
#pragma unroll
        for (int j = 0; j < 4; ++j) {
          acc[j][0] += ba.x; acc[j][1] += ba.y; acc[j][2] += ba.z; acc[j][3] += ba.w;
          acc[j][4] += bb.x; acc[j][5] += bb.y; acc[j][6] += bb.z; acc[j][7] += bb.w;
        }
      }
#pragma unroll
      for (int j = 0; j < 4; ++j) {
        int gi = nbase + ng * 4 + j;
        if (gi < n) {
          *(float4*)&O[gi * DOUT + d0] =
              make_float4(acc[j][0], acc[j][1], acc[j][2], acc[j][3]);
          *(float4*)&O[gi * DOUT + d0 + 4] =
              make_float4(acc[j][4], acc[j][5], acc[j][6], acc[j][7]);
        }
      }
    }
  }
}

// ---------------- pure aggregate: out[i] = gather_mean(Y) + out[i], act ----------------
// out already holds Z = h@Wr + b (written by k_transform2).
template <int DOUT, int ACT>
__global__ void __launch_bounds__(256) k_aggregate(const float* __restrict__ y,
                                                   const int* __restrict__ row_ptr,
                                                   const int* __restrict__ edge_src,
                                                   float* out, int n) {
  constexpr int G = DOUT / 4;  // 16 (d=64) or 10 (d=40)
  int t = threadIdx.x;
  int lane = t & 63;
  int sub = lane >> 4;  // node within wave
  int g = lane & 15;    // dim-group of 4
  int i = blockIdx.x * 16 + (t >> 6) * 4 + sub;
  if (i >= n) return;
  bool gv = (g < G);
  int gc = gv ? g : 0;
  int rp0 = row_ptr[i], rp1 = row_ptr[i + 1];
  int deg = rp1 - rp0;
  float a0 = 0.f, a1 = 0.f, a2 = 0.f, a3 = 0.f;

  for (int base = 0; base < deg; base += 16) {
    int sv = (base + g < deg) ? edge_src[rp0 + base + g] : 0;
    int cnt = min(16, deg - base);
    for (int q = 0; q < cnt; q += 4) {
#pragma unroll
      for (int u = 0; u < 4; ++u) {
        int e = q + u;
        int s = __shfl(sv, (sub << 4) | e);
        if (e < cnt) {
          const float4 v = *(const float4*)&y[s * DOUT + gc * 4];
          a0 += v.x; a1 += v.y; a2 += v.z; a3 += v.w;
        }
      }
    }
  }

  float scale = (deg > 0) ? (1.0f / (float)deg) : 0.f;
  a0 *= scale; a1 *= scale; a2 *= scale; a3 *= scale;

  const float4 z = *(const float4*)&out[i * DOUT + gc * 4];  // Z = h@Wr + b
  a0 += z.x; a1 += z.y; a2 += z.z; a3 += z.w;

  if (ACT == ACT_RELU) {
    if (gv) {
      *(float4*)&out[i * DOUT + g * 4] =
          make_float4(fmaxf(a0, 0.f), fmaxf(a1, 0.f), fmaxf(a2, 0.f), fmaxf(a3, 0.f));
    }
  } else {
    float m = gv ? fmaxf(fmaxf(a0, a1), fmaxf(a2, a3)) : -INFINITY;
#pragma unroll
    for (int off = 1; off < 16; off <<= 1) m = fmaxf(m, __shfl_xor(m, off));
    float e0 = gv ? expf(a0 - m) : 0.f;
    float e1 = gv ? expf(a1 - m) : 0.f;
    float e2 = gv ? expf(a2 - m) : 0.f;
    float e3 = gv ? expf(a3 - m) : 0.f;
    float es = ((e0 + e1) + (e2 + e3));
#pragma unroll
    for (int off = 1; off < 16; off <<= 1) es += __shfl_xor(es, off);
    float lse = logf(es);
    if (gv) {
      *(float4*)&out[i * DOUT + g * 4] =
          make_float4(a0 - m - lse, a1 - m - lse, a2 - m - lse, a3 - m - lse);
    }
  }
}

extern "C" void kernel_launch(void* const* d_in, const int* in_sizes, int n_in,
                              void* d_out, int out_size, void* d_ws, size_t ws_size,
                              hipStream_t stream) {
  const float* x   = (const float*)d_in[0];
  const int*   ei  = (const int*)d_in[1];
  const float* Wl0 = (const float*)d_in[2];
  const float* bl0 = (const float*)d_in[3];
  const float* Wr0 = (const float*)d_in[4];
  const float* Wl1 = (const float*)d_in[5];
  const float* bl1 = (const float*)d_in[6];
  const float* Wr1 = (const float*)d_in[7];
  const float* Wl2 = (const float*)d_in[8];
  const float* bl2 = (const float*)d_in[9];
  const float* Wr2 = (const float*)d_in[10];
  float* out = (float*)d_out;

  int N = in_sizes[0] / 64;
  int E = in_sizes[1] / 2;
  int M = N + 1;
  int NB = (N + 255) >> BSH;  // 391 for N=100000
  const int* src = ei;
  const int* dst = ei + E;

  char* p = (char*)d_ws;
  auto alloc = [&](size_t bytes) {
    char* r = p;
    p += (bytes + 255) & ~(size_t)255;
    return r;
  };
  int* cnt      = (int*)alloc((size_t)M * 4);
  int* row_ptr  = (int*)alloc((size_t)M * 4);
  int* cursor   = (int*)alloc((size_t)M * 4);
  int* bsum     = (int*)alloc(256 * 4);
  int* boff     = (int*)alloc(256 * 4);
  int* bk_cnt   = (int*)alloc((MAXNB + 1) * 4);
  int* bk_base  = (int*)alloc((MAXNB + 1) * 4);
  int* bk_cur   = (int*)alloc((MAXNB + 1) * 4);
  int* edge_src = (int*)alloc((size_t)E * 4);
  float* A      = (float*)alloc((size_t)N * 64 * 4);  // Y; also int2 tmp during build
  float* B      = (float*)alloc((size_t)N * 64 * 4);  // hidden states / Z
  if ((size_t)(p - (char*)d_ws) > ws_size) return;    // ws too small: fail loudly

  bool bucketed = (NB <= MAXNB) && ((size_t)E * 8 <= (size_t)N * 256);

  hipMemsetAsync(cnt, 0, (size_t)M * 4, stream);
  hipMemsetAsync(bk_cnt, 0, (MAXNB + 1) * 4, stream);
  int ebB = (E + 8191) / 8192;  // 8192-edge blocks
  k_hist2<<<ebB, 256, 0, stream>>>(dst, cnt, bk_cnt, E, NB);
  int nb = (M + 2047) / 2048;  // 49 for N=100000 (<=64 required by k_scan_mid)
  k_scan_part<<<nb, 256, 0, stream>>>(cnt, bsum, M);
  k_scan_mid<<<1, 64, 0, stream>>>(bsum, boff, nb);
  k_scan_final<<<nb, 256, 0, stream>>>(cnt, boff, row_ptr, cursor, M);
  if (bucketed) {
    k_bscan<<<1, MAXNB, 0, stream>>>(bk_cnt, bk_base, bk_cur, NB);
    k_partition<<<ebB, 256, 0, stream>>>(src, dst, bk_cur, (int2*)A, E, NB);
    k_bfill<<<NB, 256, 0, stream>>>((const int2*)A, bk_base, cursor, edge_src);
  } else {
    k_fill<<<(E + 255) / 256, 256, 0, stream>>>(src, dst, cursor, edge_src, E);
  }

  int tb = (N + 127) / 128;
  int ab = (N + 15) / 16;
  // layer 0: A = x@Wl0 ; B = x@Wr0 + bl0 ; B = relu(agg(A)/deg + B)
  k_transform2<64><<<tb, 256, 0, stream>>>(x, Wl0, Wr0, bl0, A, B, N);
  k_aggregate<64, ACT_RELU><<<ab, 256, 0, stream>>>(A, row_ptr, edge_src, B, N);
  // layer 1: A = B@Wl1 ; B <- B@Wr1 + bl1 (in-place) ; B = relu(agg(A)/deg + B)
  k_transform2<64><<<tb, 256, 0, stream>>>(B, Wl1, Wr1, bl1, A, B, N);
  k_aggregate<64, ACT_RELU><<<ab, 256, 0, stream>>>(A, row_ptr, edge_src, B, N);
  // layer 2: A = B@Wl2 ; out = B@Wr2 + bl2 ; out = log_softmax(agg(A)/deg + out)
  k_transform2<40><<<tb, 256, 0, stream>>>(B, Wl2, Wr2, bl2, A, out, N);
  k_aggregate<40, ACT_LSM><<<ab, 256, 0, stream>>>(A, row_ptr, edge_src, out, N);
}

// Round 4
// 392.181 us; speedup vs baseline: 2.0724x; 1.2117x over previous
//
#include <hip/hip_runtime.h>
#include <math.h>

#define ACT_RELU 0
#define ACT_LSM  1
#define BSH 8        // bucket = 256 consecutive dst nodes
#define MAXNB 512    // max buckets supported by the scan / LDS hist

// ---------------- CSR build (bucketed, atomic-light) ----------------
// Per-bucket histogram only: LDS atomics + one global atomic per bucket/block.
__global__ void k_histB(const int* __restrict__ dst, int* __restrict__ bucket_cnt,
                        int E, int NB) {
  __shared__ int cntL[MAXNB];
  int t = threadIdx.x;
  for (int b = t; b < NB; b += 256) cntL[b] = 0;
  __syncthreads();
  int e0 = blockIdx.x * 4096;
  int e1 = min(e0 + 4096, E);
  for (int i = e0 + t; i < e1; i += 256) atomicAdd(&cntL[dst[i] >> BSH], 1);
  __syncthreads();
  for (int b = t; b < NB; b += 256)
    if (cntL[b]) atomicAdd(&bucket_cnt[b], cntL[b]);
}

// scan of bucket counts (NB <= 512): exclusive base (+total at [NB]) and cursor
__global__ void k_bscan(const int* __restrict__ bucket_cnt, int* __restrict__ bucket_base,
                        int* __restrict__ bucket_cursor, int NB) {
  __shared__ int sm[MAXNB];
  int t = threadIdx.x;  // 512 threads
  sm[t] = (t < NB) ? bucket_cnt[t] : 0;
  __syncthreads();
  for (int off = 1; off < MAXNB; off <<= 1) {
    int x = (t >= off) ? sm[t - off] : 0;
    __syncthreads();
    sm[t] += x;
    __syncthreads();
  }
  int ex = (t == 0) ? 0 : sm[t - 1];
  if (t <= NB) bucket_base[t] = ex;
  if (t < NB) bucket_cursor[t] = ex;
}

// partition edges into dst-buckets: block reserves a contiguous range per
// bucket (1 global atomic), writes packed (src,dst) nearly line-dense.
__global__ void k_partition(const int* __restrict__ src, const int* __restrict__ dst,
                            int* __restrict__ bucket_cursor, int2* __restrict__ tmp,
                            int E, int NB) {
  __shared__ int cntL[MAXNB];
  __shared__ int baseL[MAXNB];
  int t = threadIdx.x;
  for (int b = t; b < NB; b += 256) cntL[b] = 0;
  __syncthreads();
  int e0 = blockIdx.x * 4096;
  int e1 = min(e0 + 4096, E);
  for (int i = e0 + t; i < e1; i += 256) atomicAdd(&cntL[dst[i] >> BSH], 1);
  __syncthreads();
  for (int b = t; b < NB; b += 256) {
    int c = cntL[b];
    baseL[b] = c ? atomicAdd(&bucket_cursor[b], c) : 0;
    cntL[b] = 0;  // reuse as local cursor
  }
  __syncthreads();
  for (int i = e0 + t; i < e1; i += 256) {
    int s = src[i], d = dst[i];  // second dst read is L2-hot
    int b = d >> BSH;
    int r = atomicAdd(&cntL[b], 1);
    tmp[baseL[b] + r] = make_int2(s, d);
  }
}

// One block per bucket: per-node count (LDS atomics) -> LDS scan ->
// row_ptr (coalesced, no atomics) -> fill edge_src via LDS cursors.
// Writes confined to this bucket's contiguous edge_src region.
__global__ void __launch_bounds__(256) k_bmake(const int2* __restrict__ tmp,
                                               const int* __restrict__ bucket_base,
                                               int* __restrict__ row_ptr,
                                               int* __restrict__ edge_src,
                                               int N, int E, int NB) {
  __shared__ int cntL[256];
  __shared__ int scanL[256];
  int b = blockIdx.x;
  int t = threadIdx.x;
  int e0 = bucket_base[b], e1 = bucket_base[b + 1];
  cntL[t] = 0;
  __syncthreads();
  for (int i = e0 + t; i < e1; i += 256) atomicAdd(&cntL[tmp[i].y & 255], 1);
  __syncthreads();
  int v = cntL[t];
  scanL[t] = v;
  __syncthreads();
  for (int off = 1; off < 256; off <<= 1) {
    int x = (t >= off) ? scanL[t - off] : 0;
    __syncthreads();
    scanL[t] += x;
    __syncthreads();
  }
  int exc = scanL[t] - v;          // exclusive prefix within bucket
  int node = (b << BSH) + t;
  if (node < N) row_ptr[node] = e0 + exc;
  if (b == NB - 1 && t == 0) row_ptr[N] = E;
  __syncthreads();
  cntL[t] = e0 + exc;              // reuse as cursor
  __syncthreads();
  for (int i = e0 + t; i < e1; i += 256) {
    int2 e = tmp[i];
    int p = atomicAdd(&cntL[e.y & 255], 1);   // LDS atomic
    edge_src[p] = e.x;
  }
}

// ---------------- fallback path (NB > MAXNB or tmp too big) ----------------
__global__ void k_hist(const int* __restrict__ dst, int* __restrict__ cnt, int E) {
  int i = blockIdx.x * blockDim.x + threadIdx.x;
  if (i < E) atomicAdd(&cnt[dst[i]], 1);
}

__global__ void k_scan_part(const int* __restrict__ cnt, int* __restrict__ bsum, int M) {
  __shared__ int sm[256];
  int t = threadIdx.x;
  int base = blockIdx.x * 2048 + t * 8;
  int s = 0;
#pragma unroll
  for (int j = 0; j < 8; ++j) { int i = base + j; if (i < M) s += cnt[i]; }
  sm[t] = s;
  __syncthreads();
  for (int off = 128; off > 0; off >>= 1) {
    if (t < off) sm[t] += sm[t + off];
    __syncthreads();
  }
  if (t == 0) bsum[blockIdx.x] = sm[0];
}

__global__ void k_scan_mid(const int* __restrict__ bsum, int* __restrict__ boff, int nb) {
  int l = threadIdx.x;  // 64 threads, nb <= 64
  int v = (l < nb) ? bsum[l] : 0;
  int inc = v;
  for (int off = 1; off < 64; off <<= 1) {
    int u = __shfl_up(inc, off);
    if (l >= off) inc += u;
  }
  if (l < nb) boff[l] = inc - v;
}

__global__ void k_scan_final(const int* __restrict__ cnt, const int* __restrict__ boff,
                             int* __restrict__ row_ptr, int* __restrict__ cursor, int M) {
  __shared__ int sm[256];
  int t = threadIdx.x;
  int base = blockIdx.x * 2048 + t * 8;
  int v[8];
  int s = 0;
#pragma unroll
  for (int j = 0; j < 8; ++j) { int i = base + j; v[j] = (i < M) ? cnt[i] : 0; s += v[j]; }
  sm[t] = s;
  __syncthreads();
  for (int off = 1; off < 256; off <<= 1) {
    int x = (t >= off) ? sm[t - off] : 0;
    __syncthreads();
    sm[t] += x;
    __syncthreads();
  }
  int run = boff[blockIdx.x] + sm[t] - s;
#pragma unroll
  for (int j = 0; j < 8; ++j) {
    int i = base + j;
    if (i < M) { row_ptr[i] = run; cursor[i] = run; }
    run += v[j];
  }
}

__global__ void k_fill(const int* __restrict__ src, const int* __restrict__ dst,
                       int* __restrict__ cursor, int* __restrict__ edge_src, int E) {
  int i = blockIdx.x * blockDim.x + threadIdx.x;
  if (i < E) {
    int d = dst[i];
    int p = atomicAdd(&cursor[d], 1);
    edge_src[p] = src[i];
  }
}

// ---------------- dense transform: Y = h@Wl ; Z = h@Wr + b ----------------
// Z may be written into the same buffer as h (block stages its own rows into
// LDS before overwriting; GEMM is row-to-row, no cross-row reads).
template <int DOUT>
__global__ void __launch_bounds__(256) k_transform2(const float* __restrict__ h,
                                                    const float* __restrict__ Wl,
                                                    const float* __restrict__ Wr,
                                                    const float* __restrict__ bias,
                                                    float* __restrict__ Y,
                                                    float* Z, int n) {
  __shared__ float Ws[64 * DOUT];
  __shared__ float hs[128 * 65];  // +1 pad: conflict-free column reads
  int t = threadIdx.x;
  int nbase = blockIdx.x * 128;
#pragma unroll
  for (int j = 0; j < 32; ++j) {
    int l = t + 256 * j;  // 0..8191
    int r = l >> 6, c = l & 63;
    int gi = nbase + r;
    hs[r * 65 + c] = (gi < n) ? h[gi * 64 + c] : 0.f;
  }
  int dg = t & 7, d0 = dg * 8;  // 8 dim-groups of 8 dims
  int ng = t >> 3;              // 32 node-groups of 4 nodes

  for (int pass = 0; pass < 2; ++pass) {
    const float* W = pass ? Wr : Wl;
    float* O = pass ? Z : Y;
    __syncthreads();  // pass0: hs ready; pass1: pass0 done reading Ws
    for (int l = t; l < 64 * DOUT; l += 256) Ws[l] = W[l];
    __syncthreads();
    if (d0 < DOUT) {
      float acc[4][8];
#pragma unroll
      for (int j = 0; j < 4; ++j)
#pragma unroll
        for (int c = 0; c < 8; ++c) acc[j][c] = 0.f;
#pragma unroll 4
      for (int k = 0; k < 64; ++k) {
        float4 wa = *(const float4*)&Ws[k * DOUT + d0];
        float4 wb = *(const float4*)&Ws[k * DOUT + d0 + 4];
#pragma unroll
        for (int j = 0; j < 4; ++j) {
          float hv = hs[(ng * 4 + j) * 65 + k];
          acc[j][0] += hv * wa.x; acc[j][1] += hv * wa.y;
          acc[j][2] += hv * wa.z; acc[j][3] += hv * wa.w;
          acc[j][4] += hv * wb.x; acc[j][5] += hv * wb.y;
          acc[j][6] += hv * wb.z; acc[j][7] += hv * wb.w;
        }
      }
      if (pass) {
        float4 ba = *(const float4*)&bias[d0];
        float4 bb = *(const float4*)&bias[d0 + 4];
#pragma unroll
        for (int j = 0; j < 4; ++j) {
          acc[j][0] += ba.x; acc[j][1] += ba.y; acc[j][2] += ba.z; acc[j][3] += ba.w;
          acc[j][4] += bb.x; acc[j][5] += bb.y; acc[j][6] += bb.z; acc[j][7] += bb.w;
        }
      }
#pragma unroll
      for (int j = 0; j < 4; ++j) {
        int gi = nbase + ng * 4 + j;
        if (gi < n) {
          *(float4*)&O[gi * DOUT + d0] =
              make_float4(acc[j][0], acc[j][1], acc[j][2], acc[j][3]);
          *(float4*)&O[gi * DOUT + d0 + 4] =
              make_float4(acc[j][4], acc[j][5], acc[j][6], acc[j][7]);
        }
      }
    }
  }
}

// ---------------- pure aggregate: out[i] = gather_mean(Y) + out[i], act ----------------
// out already holds Z = h@Wr + b (written by k_transform2).
template <int DOUT, int ACT>
__global__ void __launch_bounds__(256) k_aggregate(const float* __restrict__ y,
                                                   const int* __restrict__ row_ptr,
                                                   const int* __restrict__ edge_src,
                                                   float* out, int n) {
  constexpr int G = DOUT / 4;  // 16 (d=64) or 10 (d=40)
  int t = threadIdx.x;
  int lane = t & 63;
  int sub = lane >> 4;  // node within wave
  int g = lane & 15;    // dim-group of 4
  int i = blockIdx.x * 16 + (t >> 6) * 4 + sub;
  if (i >= n) return;
  bool gv = (g < G);
  int gc = gv ? g : 0;
  int rp0 = row_ptr[i], rp1 = row_ptr[i + 1];
  int deg = rp1 - rp0;
  float a0 = 0.f, a1 = 0.f, a2 = 0.f, a3 = 0.f;

  for (int base = 0; base < deg; base += 16) {
    int sv = (base + g < deg) ? edge_src[rp0 + base + g] : 0;
    int cnt = min(16, deg - base);
    for (int q = 0; q < cnt; q += 4) {
#pragma unroll
      for (int u = 0; u < 4; ++u) {
        int e = q + u;
        int s = __shfl(sv, (sub << 4) | e);
        if (e < cnt) {
          const float4 v = *(const float4*)&y[s * DOUT + gc * 4];
          a0 += v.x; a1 += v.y; a2 += v.z; a3 += v.w;
        }
      }
    }
  }

  float scale = (deg > 0) ? (1.0f / (float)deg) : 0.f;
  a0 *= scale; a1 *= scale; a2 *= scale; a3 *= scale;

  const float4 z = *(const float4*)&out[i * DOUT + gc * 4];  // Z = h@Wr + b
  a0 += z.x; a1 += z.y; a2 += z.z; a3 += z.w;

  if (ACT == ACT_RELU) {
    if (gv) {
      *(float4*)&out[i * DOUT + g * 4] =
          make_float4(fmaxf(a0, 0.f), fmaxf(a1, 0.f), fmaxf(a2, 0.f), fmaxf(a3, 0.f));
    }
  } else {
    float m = gv ? fmaxf(fmaxf(a0, a1), fmaxf(a2, a3)) : -INFINITY;
#pragma unroll
    for (int off = 1; off < 16; off <<= 1) m = fmaxf(m, __shfl_xor(m, off));
    float e0 = gv ? expf(a0 - m) : 0.f;
    float e1 = gv ? expf(a1 - m) : 0.f;
    float e2 = gv ? expf(a2 - m) : 0.f;
    float e3 = gv ? expf(a3 - m) : 0.f;
    float es = ((e0 + e1) + (e2 + e3));
#pragma unroll
    for (int off = 1; off < 16; off <<= 1) es += __shfl_xor(es, off);
    float lse = logf(es);
    if (gv) {
      *(float4*)&out[i * DOUT + g * 4] =
          make_float4(a0 - m - lse, a1 - m - lse, a2 - m - lse, a3 - m - lse);
    }
  }
}

extern "C" void kernel_launch(void* const* d_in, const int* in_sizes, int n_in,
                              void* d_out, int out_size, void* d_ws, size_t ws_size,
                              hipStream_t stream) {
  const float* x   = (const float*)d_in[0];
  const int*   ei  = (const int*)d_in[1];
  const float* Wl0 = (const float*)d_in[2];
  const float* bl0 = (const float*)d_in[3];
  const float* Wr0 = (const float*)d_in[4];
  const float* Wl1 = (const float*)d_in[5];
  const float* bl1 = (const float*)d_in[6];
  const float* Wr1 = (const float*)d_in[7];
  const float* Wl2 = (const float*)d_in[8];
  const float* bl2 = (const float*)d_in[9];
  const float* Wr2 = (const float*)d_in[10];
  float* out = (float*)d_out;

  int N = in_sizes[0] / 64;
  int E = in_sizes[1] / 2;
  int M = N + 1;
  int NB = (N + 255) >> BSH;  // 391 for N=100000
  const int* src = ei;
  const int* dst = ei + E;

  char* p = (char*)d_ws;
  auto alloc = [&](size_t bytes) {
    char* r = p;
    p += (bytes + 255) & ~(size_t)255;
    return r;
  };
  int* cnt      = (int*)alloc((size_t)M * 4);
  int* row_ptr  = (int*)alloc((size_t)M * 4);
  int* cursor   = (int*)alloc((size_t)M * 4);
  int* bsum     = (int*)alloc(256 * 4);
  int* boff     = (int*)alloc(256 * 4);
  int* bk_cnt   = (int*)alloc((MAXNB + 1) * 4);
  int* bk_base  = (int*)alloc((MAXNB + 1) * 4);
  int* bk_cur   = (int*)alloc((MAXNB + 1) * 4);
  int* edge_src = (int*)alloc((size_t)E * 4);
  float* A      = (float*)alloc((size_t)N * 64 * 4);  // Y; also int2 tmp during build
  float* B      = (float*)alloc((size_t)N * 64 * 4);  // hidden states / Z
  if ((size_t)(p - (char*)d_ws) > ws_size) return;    // ws too small: fail loudly

  bool bucketed = (NB <= MAXNB) && ((size_t)E * 8 <= (size_t)N * 256);
  int eb4 = (E + 4095) / 4096;

  if (bucketed) {
    hipMemsetAsync(bk_cnt, 0, (MAXNB + 1) * 4, stream);
    k_histB<<<eb4, 256, 0, stream>>>(dst, bk_cnt, E, NB);
    k_bscan<<<1, MAXNB, 0, stream>>>(bk_cnt, bk_base, bk_cur, NB);
    k_partition<<<eb4, 256, 0, stream>>>(src, dst, bk_cur, (int2*)A, E, NB);
    k_bmake<<<NB, 256, 0, stream>>>((const int2*)A, bk_base, row_ptr, edge_src, N, E, NB);
  } else {
    hipMemsetAsync(cnt, 0, (size_t)M * 4, stream);
    k_hist<<<(E + 255) / 256, 256, 0, stream>>>(dst, cnt, E);
    int nb = (M + 2047) / 2048;
    k_scan_part<<<nb, 256, 0, stream>>>(cnt, bsum, M);
    k_scan_mid<<<1, 64, 0, stream>>>(bsum, boff, nb);
    k_scan_final<<<nb, 256, 0, stream>>>(cnt, boff, row_ptr, cursor, M);
    k_fill<<<(E + 255) / 256, 256, 0, stream>>>(src, dst, cursor, edge_src, E);
  }

  int tb = (N + 127) / 128;
  int ab = (N + 15) / 16;
  // layer 0: A = x@Wl0 ; B = x@Wr0 + bl0 ; B = relu(agg(A)/deg + B)
  k_transform2<64><<<tb, 256, 0, stream>>>(x, Wl0, Wr0, bl0, A, B, N);
  k_aggregate<64, ACT_RELU><<<ab, 256, 0, stream>>>(A, row_ptr, edge_src, B, N);
  // layer 1: A = B@Wl1 ; B <- B@Wr1 + bl1 (in-place) ; B = relu(agg(A)/deg + B)
  k_transform2<64><<<tb, 256, 0, stream>>>(B, Wl1, Wr1, bl1, A, B, N);
  k_aggregate<64, ACT_RELU><<<ab, 256, 0, stream>>>(A, row_ptr, edge_src, B, N);
  // layer 2: A = B@Wl2 ; out = B@Wr2 + bl2 ; out = log_softmax(agg(A)/deg + out)
  k_transform2<40><<<tb, 256, 0, stream>>>(B, Wl2, Wr2, bl2, A, out, N);
  k_aggregate<40, ACT_LSM><<<ab, 256, 0, stream>>>(A, row_ptr, edge_src, out, N);
}

// Round 5
// 277.963 us; speedup vs baseline: 2.9240x; 1.4109x over previous
//
#include <hip/hip_runtime.h>
#include <math.h>

#define ACT_RELU 0
#define ACT_LSM  1
#define BSH 8        // bucket = 256 consecutive dst nodes
#define MAXNB 512    // max buckets supported by the scan / LDS hist

// bf16 helpers (OCP bf16 = top 16 bits of f32; RNE pack)
__device__ __forceinline__ unsigned f2bf(float f) {
  unsigned u = __float_as_uint(f);
  u += 0x7fffu + ((u >> 16) & 1u);
  return u >> 16;
}
__device__ __forceinline__ float bflo(unsigned u) { return __uint_as_float(u << 16); }
__device__ __forceinline__ float bfhi(unsigned u) { return __uint_as_float(u & 0xffff0000u); }

// ---------------- CSR build (bucketed, atomic-light) ----------------
__global__ void k_histB(const int* __restrict__ dst, int* __restrict__ bucket_cnt,
                        int E, int NB) {
  __shared__ int cntL[MAXNB];
  int t = threadIdx.x;
  for (int b = t; b < NB; b += 256) cntL[b] = 0;
  __syncthreads();
  int e0 = blockIdx.x * 4096;
  int e1 = min(e0 + 4096, E);
  for (int i = e0 + t; i < e1; i += 256) atomicAdd(&cntL[dst[i] >> BSH], 1);
  __syncthreads();
  for (int b = t; b < NB; b += 256)
    if (cntL[b]) atomicAdd(&bucket_cnt[b], cntL[b]);
}

__global__ void k_bscan(const int* __restrict__ bucket_cnt, int* __restrict__ bucket_base,
                        int* __restrict__ bucket_cursor, int NB) {
  __shared__ int sm[MAXNB];
  int t = threadIdx.x;  // 512 threads
  sm[t] = (t < NB) ? bucket_cnt[t] : 0;
  __syncthreads();
  for (int off = 1; off < MAXNB; off <<= 1) {
    int x = (t >= off) ? sm[t - off] : 0;
    __syncthreads();
    sm[t] += x;
    __syncthreads();
  }
  int ex = (t == 0) ? 0 : sm[t - 1];
  if (t <= NB) bucket_base[t] = ex;
  if (t < NB) bucket_cursor[t] = ex;
}

__global__ void k_partition(const int* __restrict__ src, const int* __restrict__ dst,
                            int* __restrict__ bucket_cursor, int2* __restrict__ tmp,
                            int E, int NB) {
  __shared__ int cntL[MAXNB];
  __shared__ int baseL[MAXNB];
  int t = threadIdx.x;
  for (int b = t; b < NB; b += 256) cntL[b] = 0;
  __syncthreads();
  int e0 = blockIdx.x * 4096;
  int e1 = min(e0 + 4096, E);
  for (int i = e0 + t; i < e1; i += 256) atomicAdd(&cntL[dst[i] >> BSH], 1);
  __syncthreads();
  for (int b = t; b < NB; b += 256) {
    int c = cntL[b];
    baseL[b] = c ? atomicAdd(&bucket_cursor[b], c) : 0;
    cntL[b] = 0;  // reuse as local cursor
  }
  __syncthreads();
  for (int i = e0 + t; i < e1; i += 256) {
    int s = src[i], d = dst[i];  // second dst read is L2-hot
    int b = d >> BSH;
    int r = atomicAdd(&cntL[b], 1);
    tmp[baseL[b] + r] = make_int2(s, d);
  }
}

__global__ void __launch_bounds__(256) k_bmake(const int2* __restrict__ tmp,
                                               const int* __restrict__ bucket_base,
                                               int* __restrict__ row_ptr,
                                               int* __restrict__ edge_src,
                                               int N, int E, int NB) {
  __shared__ int cntL[256];
  __shared__ int scanL[256];
  int b = blockIdx.x;
  int t = threadIdx.x;
  int e0 = bucket_base[b], e1 = bucket_base[b + 1];
  cntL[t] = 0;
  __syncthreads();
  for (int i = e0 + t; i < e1; i += 256) atomicAdd(&cntL[tmp[i].y & 255], 1);
  __syncthreads();
  int v = cntL[t];
  scanL[t] = v;
  __syncthreads();
  for (int off = 1; off < 256; off <<= 1) {
    int x = (t >= off) ? scanL[t - off] : 0;
    __syncthreads();
    scanL[t] += x;
    __syncthreads();
  }
  int exc = scanL[t] - v;
  int node = (b << BSH) + t;
  if (node < N) row_ptr[node] = e0 + exc;
  if (b == NB - 1 && t == 0) row_ptr[N] = E;
  __syncthreads();
  cntL[t] = e0 + exc;  // reuse as cursor
  __syncthreads();
  for (int i = e0 + t; i < e1; i += 256) {
    int2 e = tmp[i];
    int p = atomicAdd(&cntL[e.y & 255], 1);  // LDS atomic
    edge_src[p] = e.x;
  }
}

// ---------------- fallback path (NB > MAXNB) ----------------
__global__ void k_hist(const int* __restrict__ dst, int* __restrict__ cnt, int E) {
  int i = blockIdx.x * blockDim.x + threadIdx.x;
  if (i < E) atomicAdd(&cnt[dst[i]], 1);
}

__global__ void k_scan_part(const int* __restrict__ cnt, int* __restrict__ bsum, int M) {
  __shared__ int sm[256];
  int t = threadIdx.x;
  int base = blockIdx.x * 2048 + t * 8;
  int s = 0;
#pragma unroll
  for (int j = 0; j < 8; ++j) { int i = base + j; if (i < M) s += cnt[i]; }
  sm[t] = s;
  __syncthreads();
  for (int off = 128; off > 0; off >>= 1) {
    if (t < off) sm[t] += sm[t + off];
    __syncthreads();
  }
  if (t == 0) bsum[blockIdx.x] = sm[0];
}

__global__ void k_scan_mid(const int* __restrict__ bsum, int* __restrict__ boff, int nb) {
  int l = threadIdx.x;
  int v = (l < nb) ? bsum[l] : 0;
  int inc = v;
  for (int off = 1; off < 64; off <<= 1) {
    int u = __shfl_up(inc, off);
    if (l >= off) inc += u;
  }
  if (l < nb) boff[l] = inc - v;
}

__global__ void k_scan_final(const int* __restrict__ cnt, const int* __restrict__ boff,
                             int* __restrict__ row_ptr, int* __restrict__ cursor, int M) {
  __shared__ int sm[256];
  int t = threadIdx.x;
  int base = blockIdx.x * 2048 + t * 8;
  int v[8];
  int s = 0;
#pragma unroll
  for (int j = 0; j < 8; ++j) { int i = base + j; v[j] = (i < M) ? cnt[i] : 0; s += v[j]; }
  sm[t] = s;
  __syncthreads();
  for (int off = 1; off < 256; off <<= 1) {
    int x = (t >= off) ? sm[t - off] : 0;
    __syncthreads();
    sm[t] += x;
    __syncthreads();
  }
  int run = boff[blockIdx.x] + sm[t] - s;
#pragma unroll
  for (int j = 0; j < 8; ++j) {
    int i = base + j;
    if (i < M) { row_ptr[i] = run; cursor[i] = run; }
    run += v[j];
  }
}

__global__ void k_fill(const int* __restrict__ src, const int* __restrict__ dst,
                       int* __restrict__ cursor, int* __restrict__ edge_src, int E) {
  int i = blockIdx.x * blockDim.x + threadIdx.x;
  if (i < E) {
    int d = dst[i];
    int p = atomicAdd(&cursor[d], 1);
    edge_src[p] = src[i];
  }
}

// ---------------- dense transform: Y(bf16) = h@Wl ; Z(f32) = h@Wr + b ----------------
// 64 nodes/block, hs transposed [k][node] (pad 66) so the per-k read is one b64.
// Z may alias h (block stages its own rows into LDS before overwriting).
template <int DOUT>
__global__ void __launch_bounds__(256) k_transform2(const float* __restrict__ h,
                                                    const float* __restrict__ Wl,
                                                    const float* __restrict__ Wr,
                                                    const float* __restrict__ bias,
                                                    unsigned short* __restrict__ Y,
                                                    float* Z, int n) {
  __shared__ float Ws[64 * DOUT];
  __shared__ float hs[64 * 66];  // transposed: hs[k*66 + node]
  int t = threadIdx.x;
  int nbase = blockIdx.x * 64;
#pragma unroll
  for (int j = 0; j < 16; ++j) {
    int l = t + 256 * j;  // 0..4095
    int r = l >> 6, c = l & 63;
    int gi = nbase + r;
    hs[c * 66 + r] = (gi < n) ? h[(size_t)gi * 64 + c] : 0.f;  // 2-way bank alias: free
  }
  for (int l = t; l < 64 * DOUT; l += 256) Ws[l] = Wl[l];
  __syncthreads();

  int dg = t & 7, d0 = dg * 8;  // 8 dim-groups of 8 dims
  int ng = t >> 3;              // 32 node-groups of 2 nodes
  bool dv = (d0 < DOUT);
  int gi0 = nbase + ng * 2, gi1 = gi0 + 1;

  // ---- pass 0: Y = h@Wl, bf16 ----
  float a0[8], a1[8];
#pragma unroll
  for (int c = 0; c < 8; ++c) { a0[c] = 0.f; a1[c] = 0.f; }
  if (dv) {
#pragma unroll 4
    for (int k = 0; k < 64; ++k) {
      float2 hv = *(const float2*)&hs[k * 66 + ng * 2];
      float4 wa = *(const float4*)&Ws[k * DOUT + d0];
      float4 wb = *(const float4*)&Ws[k * DOUT + d0 + 4];
      a0[0] += hv.x * wa.x; a0[1] += hv.x * wa.y; a0[2] += hv.x * wa.z; a0[3] += hv.x * wa.w;
      a0[4] += hv.x * wb.x; a0[5] += hv.x * wb.y; a0[6] += hv.x * wb.z; a0[7] += hv.x * wb.w;
      a1[0] += hv.y * wa.x; a1[1] += hv.y * wa.y; a1[2] += hv.y * wa.z; a1[3] += hv.y * wa.w;
      a1[4] += hv.y * wb.x; a1[5] += hv.y * wb.y; a1[6] += hv.y * wb.z; a1[7] += hv.y * wb.w;
    }
    if (gi0 < n) {
      uint4 w;
      w.x = f2bf(a0[0]) | (f2bf(a0[1]) << 16);
      w.y = f2bf(a0[2]) | (f2bf(a0[3]) << 16);
      w.z = f2bf(a0[4]) | (f2bf(a0[5]) << 16);
      w.w = f2bf(a0[6]) | (f2bf(a0[7]) << 16);
      *(uint4*)(Y + (size_t)gi0 * DOUT + d0) = w;
    }
    if (gi1 < n) {
      uint4 w;
      w.x = f2bf(a1[0]) | (f2bf(a1[1]) << 16);
      w.y = f2bf(a1[2]) | (f2bf(a1[3]) << 16);
      w.z = f2bf(a1[4]) | (f2bf(a1[5]) << 16);
      w.w = f2bf(a1[6]) | (f2bf(a1[7]) << 16);
      *(uint4*)(Y + (size_t)gi1 * DOUT + d0) = w;
    }
  }

  // ---- pass 1: Z = h@Wr + b, f32 ----
  __syncthreads();  // pass0 done reading Ws
  for (int l = t; l < 64 * DOUT; l += 256) Ws[l] = Wr[l];
  __syncthreads();
  if (dv) {
#pragma unroll
    for (int c = 0; c < 8; ++c) { a0[c] = 0.f; a1[c] = 0.f; }
#pragma unroll 4
    for (int k = 0; k < 64; ++k) {
      float2 hv = *(const float2*)&hs[k * 66 + ng * 2];
      float4 wa = *(const float4*)&Ws[k * DOUT + d0];
      float4 wb = *(const float4*)&Ws[k * DOUT + d0 + 4];
      a0[0] += hv.x * wa.x; a0[1] += hv.x * wa.y; a0[2] += hv.x * wa.z; a0[3] += hv.x * wa.w;
      a0[4] += hv.x * wb.x; a0[5] += hv.x * wb.y; a0[6] += hv.x * wb.z; a0[7] += hv.x * wb.w;
      a1[0] += hv.y * wa.x; a1[1] += hv.y * wa.y; a1[2] += hv.y * wa.z; a1[3] += hv.y * wa.w;
      a1[4] += hv.y * wb.x; a1[5] += hv.y * wb.y; a1[6] += hv.y * wb.z; a1[7] += hv.y * wb.w;
    }
    float4 ba = *(const float4*)&bias[d0];
    float4 bb = *(const float4*)&bias[d0 + 4];
    if (gi0 < n) {
      *(float4*)&Z[(size_t)gi0 * DOUT + d0] =
          make_float4(a0[0] + ba.x, a0[1] + ba.y, a0[2] + ba.z, a0[3] + ba.w);
      *(float4*)&Z[(size_t)gi0 * DOUT + d0 + 4] =
          make_float4(a0[4] + bb.x, a0[5] + bb.y, a0[6] + bb.z, a0[7] + bb.w);
    }
    if (gi1 < n) {
      *(float4*)&Z[(size_t)gi1 * DOUT + d0] =
          make_float4(a1[0] + ba.x, a1[1] + ba.y, a1[2] + ba.z, a1[3] + ba.w);
      *(float4*)&Z[(size_t)gi1 * DOUT + d0 + 4] =
          make_float4(a1[4] + bb.x, a1[5] + bb.y, a1[6] + bb.z, a1[7] + bb.w);
    }
  }
}

// ---------------- aggregate: out[i] = gather_mean(Y_bf16) + out[i], act ----------------
// 8 lanes/node (16B bf16 each), 8 nodes/wave. out holds Z (f32).
template <int DOUT, int ACT>
__global__ void __launch_bounds__(256) k_aggregate(const unsigned short* __restrict__ y,
                                                   const int* __restrict__ row_ptr,
                                                   const int* __restrict__ edge_src,
                                                   float* out, int n) {
  constexpr int G = DOUT / 8;  // 8 (d=64) or 5 (d=40)
  int t = threadIdx.x;
  int lane = t & 63;
  int sub = lane >> 3;  // node within wave
  int g = lane & 7;     // dim-group of 8 bf16 (16B)
  int i = blockIdx.x * 32 + (t >> 6) * 8 + sub;
  if (i >= n) return;
  bool gv = (g < G);
  int gc = gv ? g : 0;
  int rp0 = row_ptr[i], rp1 = row_ptr[i + 1];
  int deg = rp1 - rp0;
  float a[8];
#pragma unroll
  for (int c = 0; c < 8; ++c) a[c] = 0.f;

  for (int base = 0; base < deg; base += 8) {
    int idx = rp0 + base + g;
    int sv = (idx < rp1) ? edge_src[idx] : 0;  // 8 edges per node, coalesced
    int cnt = min(8, deg - base);
    uint4 v0, v1, v2, v3, v4, v5, v6, v7;
#pragma unroll
    for (int e = 0; e < 8; ++e) {
      int s = __shfl(sv, (lane & ~7) | e);
      const uint4* p = (const uint4*)(y + (size_t)s * DOUT) + gc;
      if (e == 0 && gv && e < cnt) v0 = *p;
      if (e == 1 && gv && e < cnt) v1 = *p;
      if (e == 2 && gv && e < cnt) v2 = *p;
      if (e == 3 && gv && e < cnt) v3 = *p;
      if (e == 4 && gv && e < cnt) v4 = *p;
      if (e == 5 && gv && e < cnt) v5 = *p;
      if (e == 6 && gv && e < cnt) v6 = *p;
      if (e == 7 && gv && e < cnt) v7 = *p;
    }
#define ACCUM(vv, ee)                                                   \
    if (gv && (ee) < cnt) {                                             \
      a[0] += bflo(vv.x); a[1] += bfhi(vv.x);                           \
      a[2] += bflo(vv.y); a[3] += bfhi(vv.y);                           \
      a[4] += bflo(vv.z); a[5] += bfhi(vv.z);                           \
      a[6] += bflo(vv.w); a[7] += bfhi(vv.w);                           \
    }
    ACCUM(v0, 0) ACCUM(v1, 1) ACCUM(v2, 2) ACCUM(v3, 3)
    ACCUM(v4, 4) ACCUM(v5, 5) ACCUM(v6, 6) ACCUM(v7, 7)
#undef ACCUM
  }

  float scale = (deg > 0) ? (1.0f / (float)deg) : 0.f;
#pragma unroll
  for (int c = 0; c < 8; ++c) a[c] *= scale;

  // + Z (already in out)
  size_t ob = (size_t)i * DOUT + gc * 8;
  float4 z0 = *(const float4*)&out[ob];
  float4 z1 = *(const float4*)&out[ob + 4];
  a[0] += z0.x; a[1] += z0.y; a[2] += z0.z; a[3] += z0.w;
  a[4] += z1.x; a[5] += z1.y; a[6] += z1.z; a[7] += z1.w;

  if (ACT == ACT_RELU) {
    if (gv) {
      *(float4*)&out[ob] =
          make_float4(fmaxf(a[0], 0.f), fmaxf(a[1], 0.f), fmaxf(a[2], 0.f), fmaxf(a[3], 0.f));
      *(float4*)&out[ob + 4] =
          make_float4(fmaxf(a[4], 0.f), fmaxf(a[5], 0.f), fmaxf(a[6], 0.f), fmaxf(a[7], 0.f));
    }
  } else {
    float m = -INFINITY;
    if (gv) {
#pragma unroll
      for (int c = 0; c < 8; ++c) m = fmaxf(m, a[c]);
    }
#pragma unroll
    for (int off = 1; off < 8; off <<= 1) m = fmaxf(m, __shfl_xor(m, off));
    float es = 0.f;
    if (gv) {
#pragma unroll
      for (int c = 0; c < 8; ++c) es += expf(a[c] - m);
    }
#pragma unroll
    for (int off = 1; off < 8; off <<= 1) es += __shfl_xor(es, off);
    float lse = logf(es);
    if (gv) {
      *(float4*)&out[ob] = make_float4(a[0] - m - lse, a[1] - m - lse, a[2] - m - lse, a[3] - m - lse);
      *(float4*)&out[ob + 4] = make_float4(a[4] - m - lse, a[5] - m - lse, a[6] - m - lse, a[7] - m - lse);
    }
  }
}

extern "C" void kernel_launch(void* const* d_in, const int* in_sizes, int n_in,
                              void* d_out, int out_size, void* d_ws, size_t ws_size,
                              hipStream_t stream) {
  const float* x   = (const float*)d_in[0];
  const int*   ei  = (const int*)d_in[1];
  const float* Wl0 = (const float*)d_in[2];
  const float* bl0 = (const float*)d_in[3];
  const float* Wr0 = (const float*)d_in[4];
  const float* Wl1 = (const float*)d_in[5];
  const float* bl1 = (const float*)d_in[6];
  const float* Wr1 = (const float*)d_in[7];
  const float* Wl2 = (const float*)d_in[8];
  const float* bl2 = (const float*)d_in[9];
  const float* Wr2 = (const float*)d_in[10];
  float* out = (float*)d_out;

  int N = in_sizes[0] / 64;
  int E = in_sizes[1] / 2;
  int M = N + 1;
  int NB = (N + 255) >> BSH;  // 391 for N=100000
  const int* src = ei;
  const int* dst = ei + E;

  char* p = (char*)d_ws;
  auto alloc = [&](size_t bytes) {
    char* r = p;
    p += (bytes + 255) & ~(size_t)255;
    return r;
  };
  int* cnt      = (int*)alloc((size_t)M * 4);
  int* row_ptr  = (int*)alloc((size_t)M * 4);
  int* cursor   = (int*)alloc((size_t)M * 4);
  int* bsum     = (int*)alloc(256 * 4);
  int* boff     = (int*)alloc(256 * 4);
  int* bk_cnt   = (int*)alloc((MAXNB + 1) * 4);
  int* bk_base  = (int*)alloc((MAXNB + 1) * 4);
  int* bk_cur   = (int*)alloc((MAXNB + 1) * 4);
  int* edge_src = (int*)alloc((size_t)E * 4);
  size_t szA = (size_t)E * 8 > (size_t)N * 128 ? (size_t)E * 8 : (size_t)N * 128;
  unsigned short* A = (unsigned short*)alloc(szA);    // Y bf16; int2 tmp during build
  float* B      = (float*)alloc((size_t)N * 64 * 4);  // hidden states / Z (f32)
  if ((size_t)(p - (char*)d_ws) > ws_size) return;    // ws too small: fail loudly

  bool bucketed = (NB <= MAXNB);
  int eb4 = (E + 4095) / 4096;

  if (bucketed) {
    hipMemsetAsync(bk_cnt, 0, (MAXNB + 1) * 4, stream);
    k_histB<<<eb4, 256, 0, stream>>>(dst, bk_cnt, E, NB);
    k_bscan<<<1, MAXNB, 0, stream>>>(bk_cnt, bk_base, bk_cur, NB);
    k_partition<<<eb4, 256, 0, stream>>>(src, dst, bk_cur, (int2*)A, E, NB);
    k_bmake<<<NB, 256, 0, stream>>>((const int2*)A, bk_base, row_ptr, edge_src, N, E, NB);
  } else {
    hipMemsetAsync(cnt, 0, (size_t)M * 4, stream);
    k_hist<<<(E + 255) / 256, 256, 0, stream>>>(dst, cnt, E);
    int nb = (M + 2047) / 2048;
    k_scan_part<<<nb, 256, 0, stream>>>(cnt, bsum, M);
    k_scan_mid<<<1, 64, 0, stream>>>(bsum, boff, nb);
    k_scan_final<<<nb, 256, 0, stream>>>(cnt, boff, row_ptr, cursor, M);
    k_fill<<<(E + 255) / 256, 256, 0, stream>>>(src, dst, cursor, edge_src, E);
  }

  int tb = (N + 63) / 64;
  int ab = (N + 31) / 32;
  // layer 0: A = bf16(x@Wl0) ; B = x@Wr0 + bl0 ; B = relu(agg(A)/deg + B)
  k_transform2<64><<<tb, 256, 0, stream>>>(x, Wl0, Wr0, bl0, A, B, N);
  k_aggregate<64, ACT_RELU><<<ab, 256, 0, stream>>>(A, row_ptr, edge_src, B, N);
  // layer 1 (in-place over B)
  k_transform2<64><<<tb, 256, 0, stream>>>(B, Wl1, Wr1, bl1, A, B, N);
  k_aggregate<64, ACT_RELU><<<ab, 256, 0, stream>>>(A, row_ptr, edge_src, B, N);
  // layer 2: out = log_softmax(agg(A)/deg + (B@Wr2 + bl2))
  k_transform2<40><<<tb, 256, 0, stream>>>(B, Wl2, Wr2, bl2, A, out, N);
  k_aggregate<40, ACT_LSM><<<ab, 256, 0, stream>>>(A, row_ptr, edge_src, out, N);
}

// Round 6
// 217.408 us; speedup vs baseline: 3.7384x; 1.2785x over previous
//
#include <hip/hip_runtime.h>
#include <math.h>

#define ACT_RELU 0
#define ACT_LSM  1
#define BSH 8        // bucket = 256 consecutive dst nodes
#define MAXNB 512    // max buckets supported by the scan / LDS hist

typedef __attribute__((ext_vector_type(8))) short bf16x8;   // 8 bf16 (4 VGPRs)
typedef __attribute__((ext_vector_type(4))) float f32x4;

// bf16 helpers (OCP bf16 = top 16 bits of f32; RNE pack)
__device__ __forceinline__ unsigned f2bf(float f) {
  unsigned u = __float_as_uint(f);
  u += 0x7fffu + ((u >> 16) & 1u);
  return u >> 16;
}
__device__ __forceinline__ float bflo(unsigned u) { return __uint_as_float(u << 16); }
__device__ __forceinline__ float bfhi(unsigned u) { return __uint_as_float(u & 0xffff0000u); }

// ---------------- CSR build (bucketed, atomic-light) ----------------
__global__ void k_histB(const int* __restrict__ dst, int* __restrict__ bucket_cnt,
                        int E, int NB) {
  __shared__ int cntL[MAXNB];
  int t = threadIdx.x;
  for (int b = t; b < NB; b += 256) cntL[b] = 0;
  __syncthreads();
  int e0 = blockIdx.x * 4096;
  int e1 = min(e0 + 4096, E);
  for (int i = e0 + t; i < e1; i += 256) atomicAdd(&cntL[dst[i] >> BSH], 1);
  __syncthreads();
  for (int b = t; b < NB; b += 256)
    if (cntL[b]) atomicAdd(&bucket_cnt[b], cntL[b]);
}

__global__ void k_bscan(const int* __restrict__ bucket_cnt, int* __restrict__ bucket_base,
                        int* __restrict__ bucket_cursor, int NB) {
  __shared__ int sm[MAXNB];
  int t = threadIdx.x;  // 512 threads
  sm[t] = (t < NB) ? bucket_cnt[t] : 0;
  __syncthreads();
  for (int off = 1; off < MAXNB; off <<= 1) {
    int x = (t >= off) ? sm[t - off] : 0;
    __syncthreads();
    sm[t] += x;
    __syncthreads();
  }
  int ex = (t == 0) ? 0 : sm[t - 1];
  if (t <= NB) bucket_base[t] = ex;
  if (t < NB) bucket_cursor[t] = ex;
}

__global__ void k_partition(const int* __restrict__ src, const int* __restrict__ dst,
                            int* __restrict__ bucket_cursor, int2* __restrict__ tmp,
                            int E, int NB) {
  __shared__ int cntL[MAXNB];
  __shared__ int baseL[MAXNB];
  int t = threadIdx.x;
  for (int b = t; b < NB; b += 256) cntL[b] = 0;
  __syncthreads();
  int e0 = blockIdx.x * 4096;
  int e1 = min(e0 + 4096, E);
  for (int i = e0 + t; i < e1; i += 256) atomicAdd(&cntL[dst[i] >> BSH], 1);
  __syncthreads();
  for (int b = t; b < NB; b += 256) {
    int c = cntL[b];
    baseL[b] = c ? atomicAdd(&bucket_cursor[b], c) : 0;
    cntL[b] = 0;  // reuse as local cursor
  }
  __syncthreads();
  for (int i = e0 + t; i < e1; i += 256) {
    int s = src[i], d = dst[i];  // second dst read is L2-hot
    int b = d >> BSH;
    int r = atomicAdd(&cntL[b], 1);
    tmp[baseL[b] + r] = make_int2(s, d);
  }
}

__global__ void __launch_bounds__(256) k_bmake(const int2* __restrict__ tmp,
                                               const int* __restrict__ bucket_base,
                                               int* __restrict__ row_ptr,
                                               int* __restrict__ edge_src,
                                               int N, int E, int NB) {
  __shared__ int cntL[256];
  __shared__ int scanL[256];
  int b = blockIdx.x;
  int t = threadIdx.x;
  int e0 = bucket_base[b], e1 = bucket_base[b + 1];
  cntL[t] = 0;
  __syncthreads();
  for (int i = e0 + t; i < e1; i += 256) atomicAdd(&cntL[tmp[i].y & 255], 1);
  __syncthreads();
  int v = cntL[t];
  scanL[t] = v;
  __syncthreads();
  for (int off = 1; off < 256; off <<= 1) {
    int x = (t >= off) ? scanL[t - off] : 0;
    __syncthreads();
    scanL[t] += x;
    __syncthreads();
  }
  int exc = scanL[t] - v;
  int node = (b << BSH) + t;
  if (node < N) row_ptr[node] = e0 + exc;
  if (b == NB - 1 && t == 0) row_ptr[N] = E;
  __syncthreads();
  cntL[t] = e0 + exc;  // reuse as cursor
  __syncthreads();
  for (int i = e0 + t; i < e1; i += 256) {
    int2 e = tmp[i];
    int p = atomicAdd(&cntL[e.y & 255], 1);  // LDS atomic
    edge_src[p] = e.x;
  }
}

// ---------------- fallback path (NB > MAXNB) ----------------
__global__ void k_hist(const int* __restrict__ dst, int* __restrict__ cnt, int E) {
  int i = blockIdx.x * blockDim.x + threadIdx.x;
  if (i < E) atomicAdd(&cnt[dst[i]], 1);
}

__global__ void k_scan_part(const int* __restrict__ cnt, int* __restrict__ bsum, int M) {
  __shared__ int sm[256];
  int t = threadIdx.x;
  int base = blockIdx.x * 2048 + t * 8;
  int s = 0;
#pragma unroll
  for (int j = 0; j < 8; ++j) { int i = base + j; if (i < M) s += cnt[i]; }
  sm[t] = s;
  __syncthreads();
  for (int off = 128; off > 0; off >>= 1) {
    if (t < off) sm[t] += sm[t + off];
    __syncthreads();
  }
  if (t == 0) bsum[blockIdx.x] = sm[0];
}

__global__ void k_scan_mid(const int* __restrict__ bsum, int* __restrict__ boff, int nb) {
  int l = threadIdx.x;
  int v = (l < nb) ? bsum[l] : 0;
  int inc = v;
  for (int off = 1; off < 64; off <<= 1) {
    int u = __shfl_up(inc, off);
    if (l >= off) inc += u;
  }
  if (l < nb) boff[l] = inc - v;
}

__global__ void k_scan_final(const int* __restrict__ cnt, const int* __restrict__ boff,
                             int* __restrict__ row_ptr, int* __restrict__ cursor, int M) {
  __shared__ int sm[256];
  int t = threadIdx.x;
  int base = blockIdx.x * 2048 + t * 8;
  int v[8];
  int s = 0;
#pragma unroll
  for (int j = 0; j < 8; ++j) { int i = base + j; v[j] = (i < M) ? cnt[i] : 0; s += v[j]; }
  sm[t] = s;
  __syncthreads();
  for (int off = 1; off < 256; off <<= 1) {
    int x = (t >= off) ? sm[t - off] : 0;
    __syncthreads();
    sm[t] += x;
    __syncthreads();
  }
  int run = boff[blockIdx.x] + sm[t] - s;
#pragma unroll
  for (int j = 0; j < 8; ++j) {
    int i = base + j;
    if (i < M) { row_ptr[i] = run; cursor[i] = run; }
    run += v[j];
  }
}

__global__ void k_fill(const int* __restrict__ src, const int* __restrict__ dst,
                       int* __restrict__ cursor, int* __restrict__ edge_src, int E) {
  int i = blockIdx.x * blockDim.x + threadIdx.x;
  if (i < E) {
    int d = dst[i];
    int p = atomicAdd(&cursor[d], 1);
    edge_src[p] = src[i];
  }
}

// ---------------- cast f32 -> bf16 (8 elems/thread) ----------------
__global__ void __launch_bounds__(256) k_cast(const float* __restrict__ x,
                                              unsigned short* __restrict__ xb, int n) {
  int i = blockIdx.x * 256 + threadIdx.x;  // unit of 8 elements
  if (i * 8 < n) {
    const float4* p = (const float4*)(x + (size_t)i * 8);
    float4 a = p[0], b = p[1];
    uint4 w;
    w.x = f2bf(a.x) | (f2bf(a.y) << 16);
    w.y = f2bf(a.z) | (f2bf(a.w) << 16);
    w.z = f2bf(b.x) | (f2bf(b.y) << 16);
    w.w = f2bf(b.z) | (f2bf(b.w) << 16);
    *(uint4*)(xb + (size_t)i * 8) = w;
  }
}

// ---------------- aggregate: Mb[i] = bf16(mean_{j in N(i)} h[j]) ----------------
// h, Mb bf16 [N][64]. 8 lanes/node (16B each), 8 nodes/wave, f32 accumulate.
__global__ void __launch_bounds__(256) k_aggmean(const unsigned short* __restrict__ h,
                                                 const int* __restrict__ row_ptr,
                                                 const int* __restrict__ edge_src,
                                                 unsigned short* __restrict__ Mb, int n) {
  int t = threadIdx.x;
  int lane = t & 63;
  int g = lane & 7;  // dim-group of 8 bf16 (16B)
  int i = blockIdx.x * 32 + (t >> 6) * 8 + (lane >> 3);
  if (i >= n) return;
  int rp0 = row_ptr[i], rp1 = row_ptr[i + 1];
  int deg = rp1 - rp0;
  float a[8];
#pragma unroll
  for (int c = 0; c < 8; ++c) a[c] = 0.f;

  for (int base = 0; base < deg; base += 8) {
    int idx = rp0 + base + g;
    int sv = (idx < rp1) ? edge_src[idx] : 0;  // 8 edges per node, coalesced
    int cnt = min(8, deg - base);
    uint4 v0, v1, v2, v3, v4, v5, v6, v7;
#pragma unroll
    for (int e = 0; e < 8; ++e) {
      int s = __shfl(sv, (lane & ~7) | e);
      const uint4* p = (const uint4*)(h + (size_t)s * 64) + g;
      if (e == 0 && e < cnt) v0 = *p;
      if (e == 1 && e < cnt) v1 = *p;
      if (e == 2 && e < cnt) v2 = *p;
      if (e == 3 && e < cnt) v3 = *p;
      if (e == 4 && e < cnt) v4 = *p;
      if (e == 5 && e < cnt) v5 = *p;
      if (e == 6 && e < cnt) v6 = *p;
      if (e == 7 && e < cnt) v7 = *p;
    }
#define ACCUM(vv, ee)                                                   \
    if ((ee) < cnt) {                                                   \
      a[0] += bflo(vv.x); a[1] += bfhi(vv.x);                           \
      a[2] += bflo(vv.y); a[3] += bfhi(vv.y);                           \
      a[4] += bflo(vv.z); a[5] += bfhi(vv.z);                           \
      a[6] += bflo(vv.w); a[7] += bfhi(vv.w);                           \
    }
    ACCUM(v0, 0) ACCUM(v1, 1) ACCUM(v2, 2) ACCUM(v3, 3)
    ACCUM(v4, 4) ACCUM(v5, 5) ACCUM(v6, 6) ACCUM(v7, 7)
#undef ACCUM
  }

  float scale = (deg > 0) ? (1.0f / (float)deg) : 0.f;
  uint4 w;
  w.x = f2bf(a[0] * scale) | (f2bf(a[1] * scale) << 16);
  w.y = f2bf(a[2] * scale) | (f2bf(a[3] * scale) << 16);
  w.z = f2bf(a[4] * scale) | (f2bf(a[5] * scale) << 16);
  w.w = f2bf(a[6] * scale) | (f2bf(a[7] * scale) << 16);
  *((uint4*)(Mb + (size_t)i * 64) + g) = w;
}

// ---------------- MFMA GEMM: out = act([Ma, Ha] @ [Wl; Wr] + b) ----------------
// K = 128 (64 from Ma, 64 from Ha), bf16 inputs, f32 accumulate.
// 4 waves/block, 16 rows/wave. W staged once in LDS (fragment-linear bf16).
// mfma_f32_16x16x32_bf16 layouts: A row = lane&15, k = (lane>>4)*8 + j;
// B col = lane&15, same k; C/D col = lane&15, row = (lane>>4)*4 + reg.
template <int DOUT, int ACT>
__global__ void __launch_bounds__(256) k_gemm(const unsigned short* __restrict__ Ma,
                                              const unsigned short* __restrict__ Ha,
                                              const float* __restrict__ Wl,
                                              const float* __restrict__ Wr,
                                              const float* __restrict__ bias,
                                              void* __restrict__ outv, int n) {
  constexpr int NT = (DOUT + 15) / 16;  // 4 (d=64) or 3 (d=40)
  constexpr int PADN = NT * 16;
  __shared__ unsigned short Wlds[128 * PADN];
  int t = threadIdx.x;
  for (int idx = t; idx < 128 * PADN; idx += 256) {
    int k = idx / PADN, nn = idx % PADN;
    float v = 0.f;
    if (nn < DOUT) v = (k < 64) ? Wl[k * DOUT + nn] : Wr[(k - 64) * DOUT + nn];
    int fi = ((((k >> 5) * NT + (nn >> 4)) * 16 + (nn & 15)) * 4 + ((k >> 3) & 3)) * 8 + (k & 7);
    Wlds[fi] = (unsigned short)f2bf(v);
  }
  __syncthreads();

  int lane = t & 63;
  int c = lane & 15;   // col within tile / row within A-frag
  int kb = lane >> 4;  // k-block (8 consecutive k)

  bf16x8 bf[4][NT];
#pragma unroll
  for (int s = 0; s < 4; ++s)
#pragma unroll
    for (int nt = 0; nt < NT; ++nt)
      bf[s][nt] = *(const bf16x8*)&Wlds[(((s * NT + nt) * 16 + c) * 4 + kb) * 8];

  int r0 = (blockIdx.x * 4 + (t >> 6)) * 16;
  int row = r0 + c;
  if (row >= n) row = n - 1;  // clamp loads; stores are guarded
  size_t rb = (size_t)row * 64 + kb * 8;
  bf16x8 af[4];
  af[0] = *(const bf16x8*)(Ma + rb);
  af[1] = *(const bf16x8*)(Ma + rb + 32);
  af[2] = *(const bf16x8*)(Ha + rb);
  af[3] = *(const bf16x8*)(Ha + rb + 32);

  f32x4 acc[NT];
#pragma unroll
  for (int nt = 0; nt < NT; ++nt) acc[nt] = (f32x4){0.f, 0.f, 0.f, 0.f};
#pragma unroll
  for (int s = 0; s < 4; ++s)
#pragma unroll
    for (int nt = 0; nt < NT; ++nt)
      acc[nt] = __builtin_amdgcn_mfma_f32_16x16x32_bf16(af[s], bf[s][nt], acc[nt], 0, 0, 0);

  int rbase = r0 + kb * 4;
  if (ACT == ACT_RELU) {
    unsigned short* out = (unsigned short*)outv;
#pragma unroll
    for (int nt = 0; nt < NT; ++nt) {
      float bval = bias[nt * 16 + c];
#pragma unroll
      for (int r = 0; r < 4; ++r) {
        int R = rbase + r;
        if (R < n) {
          float v = fmaxf(acc[nt][r] + bval, 0.f);
          out[(size_t)R * DOUT + nt * 16 + c] = (unsigned short)f2bf(v);
        }
      }
    }
  } else {
    float* out = (float*)outv;
    float bv[NT];
#pragma unroll
    for (int nt = 0; nt < NT; ++nt) bv[nt] = ((nt * 16 + c) < DOUT) ? bias[nt * 16 + c] : 0.f;
#pragma unroll
    for (int r = 0; r < 4; ++r) {
      int R = rbase + r;
      float v[NT];
      float m = -INFINITY;
#pragma unroll
      for (int nt = 0; nt < NT; ++nt) {
        bool valid = (nt * 16 + c) < DOUT;
        v[nt] = valid ? (acc[nt][r] + bv[nt]) : -INFINITY;
        m = fmaxf(m, v[nt]);
      }
#pragma unroll
      for (int off = 1; off < 16; off <<= 1) m = fmaxf(m, __shfl_xor(m, off));
      float es = 0.f;
#pragma unroll
      for (int nt = 0; nt < NT; ++nt)
        if ((nt * 16 + c) < DOUT) es += expf(v[nt] - m);
#pragma unroll
      for (int off = 1; off < 16; off <<= 1) es += __shfl_xor(es, off);
      float lse = logf(es);
      if (R < n) {
#pragma unroll
        for (int nt = 0; nt < NT; ++nt)
          if ((nt * 16 + c) < DOUT) out[(size_t)R * DOUT + nt * 16 + c] = v[nt] - m - lse;
      }
    }
  }
}

extern "C" void kernel_launch(void* const* d_in, const int* in_sizes, int n_in,
                              void* d_out, int out_size, void* d_ws, size_t ws_size,
                              hipStream_t stream) {
  const float* x   = (const float*)d_in[0];
  const int*   ei  = (const int*)d_in[1];
  const float* Wl0 = (const float*)d_in[2];
  const float* bl0 = (const float*)d_in[3];
  const float* Wr0 = (const float*)d_in[4];
  const float* Wl1 = (const float*)d_in[5];
  const float* bl1 = (const float*)d_in[6];
  const float* Wr1 = (const float*)d_in[7];
  const float* Wl2 = (const float*)d_in[8];
  const float* bl2 = (const float*)d_in[9];
  const float* Wr2 = (const float*)d_in[10];
  float* out = (float*)d_out;

  int N = in_sizes[0] / 64;
  int E = in_sizes[1] / 2;
  int M = N + 1;
  int NB = (N + 255) >> BSH;  // 391 for N=100000
  const int* src = ei;
  const int* dst = ei + E;

  char* p = (char*)d_ws;
  auto alloc = [&](size_t bytes) {
    char* r = p;
    p += (bytes + 255) & ~(size_t)255;
    return r;
  };
  int* cnt      = (int*)alloc((size_t)M * 4);
  int* row_ptr  = (int*)alloc((size_t)M * 4);
  int* cursor   = (int*)alloc((size_t)M * 4);
  int* bsum     = (int*)alloc(256 * 4);
  int* boff     = (int*)alloc(256 * 4);
  int* bk_cnt   = (int*)alloc((MAXNB + 1) * 4);
  int* bk_base  = (int*)alloc((MAXNB + 1) * 4);
  int* bk_cur   = (int*)alloc((MAXNB + 1) * 4);
  int* edge_src = (int*)alloc((size_t)E * 4);
  // R1: int2 tmp during CSR build, then xb (bf16 x), then hbB (layer-1 output)
  size_t szR1 = (size_t)E * 8 > (size_t)N * 128 ? (size_t)E * 8 : (size_t)N * 128;
  char* R1              = alloc(szR1);
  unsigned short* Mb    = (unsigned short*)alloc((size_t)N * 128);  // aggregate (bf16)
  unsigned short* hbA   = (unsigned short*)alloc((size_t)N * 128);  // hidden (bf16)
  if ((size_t)(p - (char*)d_ws) > ws_size) return;  // ws too small: fail loudly

  bool bucketed = (NB <= MAXNB);
  int eb4 = (E + 4095) / 4096;

  if (bucketed) {
    hipMemsetAsync(bk_cnt, 0, (MAXNB + 1) * 4, stream);
    k_histB<<<eb4, 256, 0, stream>>>(dst, bk_cnt, E, NB);
    k_bscan<<<1, MAXNB, 0, stream>>>(bk_cnt, bk_base, bk_cur, NB);
    k_partition<<<eb4, 256, 0, stream>>>(src, dst, bk_cur, (int2*)R1, E, NB);
    k_bmake<<<NB, 256, 0, stream>>>((const int2*)R1, bk_base, row_ptr, edge_src, N, E, NB);
  } else {
    hipMemsetAsync(cnt, 0, (size_t)M * 4, stream);
    k_hist<<<(E + 255) / 256, 256, 0, stream>>>(dst, cnt, E);
    int nb = (M + 2047) / 2048;
    k_scan_part<<<nb, 256, 0, stream>>>(cnt, bsum, M);
    k_scan_mid<<<1, 64, 0, stream>>>(bsum, boff, nb);
    k_scan_final<<<nb, 256, 0, stream>>>(cnt, boff, row_ptr, cursor, M);
    k_fill<<<(E + 255) / 256, 256, 0, stream>>>(src, dst, cursor, edge_src, E);
  }

  unsigned short* xb  = (unsigned short*)R1;  // reuses tmp region (tmp dead after k_bmake)
  unsigned short* hbB = (unsigned short*)R1;  // reused again after xb is dead

  int cb = (N * 64 / 8 + 255) / 256;
  int ab = (N + 31) / 32;
  int gb = (N + 63) / 64;

  k_cast<<<cb, 256, 0, stream>>>(x, xb, N * 64);
  // layer 0: M0 = mean_agg(xb) ; hbA = relu([M0, xb] @ [Wl0; Wr0] + bl0)
  k_aggmean<<<ab, 256, 0, stream>>>(xb, row_ptr, edge_src, Mb, N);
  k_gemm<64, ACT_RELU><<<gb, 256, 0, stream>>>(Mb, xb, Wl0, Wr0, bl0, hbA, N);
  // layer 1: M1 = mean_agg(hbA) ; hbB = relu([M1, hbA] @ [Wl1; Wr1] + bl1)
  k_aggmean<<<ab, 256, 0, stream>>>(hbA, row_ptr, edge_src, Mb, N);
  k_gemm<64, ACT_RELU><<<gb, 256, 0, stream>>>(Mb, hbA, Wl1, Wr1, bl1, hbB, N);
  // layer 2: M2 = mean_agg(hbB) ; out = log_softmax([M2, hbB] @ [Wl2; Wr2] + bl2)
  k_aggmean<<<ab, 256, 0, stream>>>(hbB, row_ptr, edge_src, Mb, N);
  k_gemm<40, ACT_LSM><<<gb, 256, 0, stream>>>(Mb, hbB, Wl2, Wr2, bl2, out, N);
}

// Round 7
// 208.823 us; speedup vs baseline: 3.8921x; 1.0411x over previous
//
#include <hip/hip_runtime.h>
#include <math.h>

#define ACT_RELU 0
#define ACT_LSM  1
#define BSH 8        // bucket = 256 consecutive dst nodes
#define MAXNB 512    // max buckets supported by the scan / LDS hist

typedef __attribute__((ext_vector_type(8))) short bf16x8;   // 8 bf16 (4 VGPRs)
typedef __attribute__((ext_vector_type(4))) float f32x4;

// bf16 helpers (OCP bf16 = top 16 bits of f32; RNE pack)
__device__ __forceinline__ unsigned f2bf(float f) {
  unsigned u = __float_as_uint(f);
  u += 0x7fffu + ((u >> 16) & 1u);
  return u >> 16;
}
__device__ __forceinline__ float bflo(unsigned u) { return __uint_as_float(u << 16); }
__device__ __forceinline__ float bfhi(unsigned u) { return __uint_as_float(u & 0xffff0000u); }

// ---------------- tiny zero (replaces in-graph hipMemsetAsync) ----------------
__global__ void k_zero(int* __restrict__ p, int n) {
  int i = blockIdx.x * 256 + threadIdx.x;
  if (i < n) p[i] = 0;
}

// ---------------- CSR build (bucketed, atomic-light) ----------------
__global__ void k_histB(const int* __restrict__ dst, int* __restrict__ bucket_cnt,
                        int E, int NB) {
  __shared__ int cntL[MAXNB];
  int t = threadIdx.x;
  for (int b = t; b < NB; b += 256) cntL[b] = 0;
  __syncthreads();
  int e0 = blockIdx.x * 4096;
  int e1 = min(e0 + 4096, E);
  for (int i = e0 + t; i < e1; i += 256) atomicAdd(&cntL[dst[i] >> BSH], 1);
  __syncthreads();
  for (int b = t; b < NB; b += 256)
    if (cntL[b]) atomicAdd(&bucket_cnt[b], cntL[b]);
}

__global__ void k_bscan(const int* __restrict__ bucket_cnt, int* __restrict__ bucket_base,
                        int* __restrict__ bucket_cursor, int NB) {
  __shared__ int sm[MAXNB];
  int t = threadIdx.x;  // 512 threads
  sm[t] = (t < NB) ? bucket_cnt[t] : 0;
  __syncthreads();
  for (int off = 1; off < MAXNB; off <<= 1) {
    int x = (t >= off) ? sm[t - off] : 0;
    __syncthreads();
    sm[t] += x;
    __syncthreads();
  }
  int ex = (t == 0) ? 0 : sm[t - 1];
  if (t <= NB) bucket_base[t] = ex;
  if (t < NB) bucket_cursor[t] = ex;
}

__global__ void k_partition(const int* __restrict__ src, const int* __restrict__ dst,
                            int* __restrict__ bucket_cursor, int2* __restrict__ tmp,
                            int E, int NB) {
  __shared__ int cntL[MAXNB];
  __shared__ int baseL[MAXNB];
  int t = threadIdx.x;
  for (int b = t; b < NB; b += 256) cntL[b] = 0;
  __syncthreads();
  int e0 = blockIdx.x * 4096;
  int e1 = min(e0 + 4096, E);
  for (int i = e0 + t; i < e1; i += 256) atomicAdd(&cntL[dst[i] >> BSH], 1);
  __syncthreads();
  for (int b = t; b < NB; b += 256) {
    int c = cntL[b];
    baseL[b] = c ? atomicAdd(&bucket_cursor[b], c) : 0;
    cntL[b] = 0;  // reuse as local cursor
  }
  __syncthreads();
  for (int i = e0 + t; i < e1; i += 256) {
    int s = src[i], d = dst[i];  // second dst read is L2-hot
    int b = d >> BSH;
    int r = atomicAdd(&cntL[b], 1);
    tmp[baseL[b] + r] = make_int2(s, d);
  }
}

__global__ void __launch_bounds__(256) k_bmake(const int2* __restrict__ tmp,
                                               const int* __restrict__ bucket_base,
                                               int* __restrict__ row_ptr,
                                               int* __restrict__ edge_src,
                                               int N, int E, int NB) {
  __shared__ int cntL[256];
  __shared__ int scanL[256];
  int b = blockIdx.x;
  int t = threadIdx.x;
  int e0 = bucket_base[b], e1 = bucket_base[b + 1];
  cntL[t] = 0;
  __syncthreads();
  for (int i = e0 + t; i < e1; i += 256) atomicAdd(&cntL[tmp[i].y & 255], 1);
  __syncthreads();
  int v = cntL[t];
  scanL[t] = v;
  __syncthreads();
  for (int off = 1; off < 256; off <<= 1) {
    int x = (t >= off) ? scanL[t - off] : 0;
    __syncthreads();
    scanL[t] += x;
    __syncthreads();
  }
  int exc = scanL[t] - v;
  int node = (b << BSH) + t;
  if (node < N) row_ptr[node] = e0 + exc;
  if (b == NB - 1 && t == 0) row_ptr[N] = E;
  __syncthreads();
  cntL[t] = e0 + exc;  // reuse as cursor
  __syncthreads();
  for (int i = e0 + t; i < e1; i += 256) {
    int2 e = tmp[i];
    int p = atomicAdd(&cntL[e.y & 255], 1);  // LDS atomic
    edge_src[p] = e.x;
  }
}

// ---------------- fallback path (NB > MAXNB) ----------------
__global__ void k_hist(const int* __restrict__ dst, int* __restrict__ cnt, int E) {
  int i = blockIdx.x * blockDim.x + threadIdx.x;
  if (i < E) atomicAdd(&cnt[dst[i]], 1);
}

__global__ void k_scan_part(const int* __restrict__ cnt, int* __restrict__ bsum, int M) {
  __shared__ int sm[256];
  int t = threadIdx.x;
  int base = blockIdx.x * 2048 + t * 8;
  int s = 0;
#pragma unroll
  for (int j = 0; j < 8; ++j) { int i = base + j; if (i < M) s += cnt[i]; }
  sm[t] = s;
  __syncthreads();
  for (int off = 128; off > 0; off >>= 1) {
    if (t < off) sm[t] += sm[t + off];
    __syncthreads();
  }
  if (t == 0) bsum[blockIdx.x] = sm[0];
}

__global__ void k_scan_mid(const int* __restrict__ bsum, int* __restrict__ boff, int nb) {
  int l = threadIdx.x;
  int v = (l < nb) ? bsum[l] : 0;
  int inc = v;
  for (int off = 1; off < 64; off <<= 1) {
    int u = __shfl_up(inc, off);
    if (l >= off) inc += u;
  }
  if (l < nb) boff[l] = inc - v;
}

__global__ void k_scan_final(const int* __restrict__ cnt, const int* __restrict__ boff,
                             int* __restrict__ row_ptr, int* __restrict__ cursor, int M) {
  __shared__ int sm[256];
  int t = threadIdx.x;
  int base = blockIdx.x * 2048 + t * 8;
  int v[8];
  int s = 0;
#pragma unroll
  for (int j = 0; j < 8; ++j) { int i = base + j; v[j] = (i < M) ? cnt[i] : 0; s += v[j]; }
  sm[t] = s;
  __syncthreads();
  for (int off = 1; off < 256; off <<= 1) {
    int x = (t >= off) ? sm[t - off] : 0;
    __syncthreads();
    sm[t] += x;
    __syncthreads();
  }
  int run = boff[blockIdx.x] + sm[t] - s;
#pragma unroll
  for (int j = 0; j < 8; ++j) {
    int i = base + j;
    if (i < M) { row_ptr[i] = run; cursor[i] = run; }
    run += v[j];
  }
}

__global__ void k_fill(const int* __restrict__ src, const int* __restrict__ dst,
                       int* __restrict__ cursor, int* __restrict__ edge_src, int E) {
  int i = blockIdx.x * blockDim.x + threadIdx.x;
  if (i < E) {
    int d = dst[i];
    int p = atomicAdd(&cursor[d], 1);
    edge_src[p] = src[i];
  }
}

// ---------------- cast f32 -> bf16 (8 elems/thread) ----------------
__global__ void __launch_bounds__(256) k_cast(const float* __restrict__ x,
                                              unsigned short* __restrict__ xb, int n) {
  int i = blockIdx.x * 256 + threadIdx.x;  // unit of 8 elements
  if (i * 8 < n) {
    const float4* p = (const float4*)(x + (size_t)i * 8);
    float4 a = p[0], b = p[1];
    uint4 w;
    w.x = f2bf(a.x) | (f2bf(a.y) << 16);
    w.y = f2bf(a.z) | (f2bf(a.w) << 16);
    w.z = f2bf(b.x) | (f2bf(b.y) << 16);
    w.w = f2bf(b.z) | (f2bf(b.w) << 16);
    *(uint4*)(xb + (size_t)i * 8) = w;
  }
}

// ---------------- fused SAGE layer: out = act([mean_agg(h), h] @ [Wl; Wr] + b) ----------------
// 4 waves/block, 16 rows/wave, 64 rows/block. Per wave:
//   phase A: gather-mean its 16 rows (8 lanes/node, bf16 rows, f32 accum) -> LDS (72-pad)
//   phase B: MFMA K=128 (frags: mean from LDS, own-rows from global, W from LDS)
// mfma_f32_16x16x32_bf16: A row = lane&15, k = (lane>>4)*8+j; C/D col = lane&15,
// row = (lane>>4)*4 + reg  [verified R6: passed with this mapping].
template <int DOUT, int ACT>
__global__ void __launch_bounds__(256) k_layer(const unsigned short* __restrict__ h,
                                               const int* __restrict__ row_ptr,
                                               const int* __restrict__ edge_src,
                                               const float* __restrict__ Wl,
                                               const float* __restrict__ Wr,
                                               const float* __restrict__ bias,
                                               void* __restrict__ outv, int n) {
  constexpr int NT = (DOUT + 15) / 16;  // 4 (d=64) or 3 (d=40)
  constexpr int PADN = NT * 16;
  __shared__ unsigned short Wlds[128 * PADN];
  __shared__ unsigned short meanL[4][16 * 72];  // per-wave mean tile, 72-ushort pad
  int t = threadIdx.x;

  // stage W (fragment-linear bf16)
  for (int idx = t; idx < 128 * PADN; idx += 256) {
    int k = idx / PADN, nn = idx % PADN;
    float v = 0.f;
    if (nn < DOUT) v = (k < 64) ? Wl[k * DOUT + nn] : Wr[(k - 64) * DOUT + nn];
    int fi = ((((k >> 5) * NT + (nn >> 4)) * 16 + (nn & 15)) * 4 + ((k >> 3) & 3)) * 8 + (k & 7);
    Wlds[fi] = (unsigned short)f2bf(v);
  }

  int w = t >> 6, lane = t & 63;
  int r0 = (blockIdx.x * 4 + w) * 16;  // wave's 16 rows
  int g = lane & 7;                    // dim-group of 8 bf16 (16B)

  // ---- phase A: gather-mean, two batches of 8 nodes ----
  for (int half = 0; half < 2; ++half) {
    int node = half * 8 + (lane >> 3);
    int i = r0 + node;
    float a[8];
#pragma unroll
    for (int c = 0; c < 8; ++c) a[c] = 0.f;
    float scale = 0.f;
    if (i < n) {
      int rp0 = row_ptr[i], rp1 = row_ptr[i + 1];
      int deg = rp1 - rp0;
      scale = (deg > 0) ? (1.0f / (float)deg) : 0.f;
      for (int base = 0; base < deg; base += 8) {
        int idx = rp0 + base + g;
        int sv = (idx < rp1) ? edge_src[idx] : 0;  // 8 edges per node, coalesced
        int cnt = min(8, deg - base);
        uint4 v0, v1, v2, v3, v4, v5, v6, v7;
#pragma unroll
        for (int e = 0; e < 8; ++e) {
          int s = __shfl(sv, (lane & ~7) | e);
          const uint4* p = (const uint4*)(h + (size_t)s * 64) + g;
          if (e == 0 && e < cnt) v0 = *p;
          if (e == 1 && e < cnt) v1 = *p;
          if (e == 2 && e < cnt) v2 = *p;
          if (e == 3 && e < cnt) v3 = *p;
          if (e == 4 && e < cnt) v4 = *p;
          if (e == 5 && e < cnt) v5 = *p;
          if (e == 6 && e < cnt) v6 = *p;
          if (e == 7 && e < cnt) v7 = *p;
        }
#define ACCUM(vv, ee)                                                   \
        if ((ee) < cnt) {                                               \
          a[0] += bflo(vv.x); a[1] += bfhi(vv.x);                       \
          a[2] += bflo(vv.y); a[3] += bfhi(vv.y);                       \
          a[4] += bflo(vv.z); a[5] += bfhi(vv.z);                       \
          a[6] += bflo(vv.w); a[7] += bfhi(vv.w);                       \
        }
        ACCUM(v0, 0) ACCUM(v1, 1) ACCUM(v2, 2) ACCUM(v3, 3)
        ACCUM(v4, 4) ACCUM(v5, 5) ACCUM(v6, 6) ACCUM(v7, 7)
#undef ACCUM
      }
    }
    uint4 wv;
    wv.x = f2bf(a[0] * scale) | (f2bf(a[1] * scale) << 16);
    wv.y = f2bf(a[2] * scale) | (f2bf(a[3] * scale) << 16);
    wv.z = f2bf(a[4] * scale) | (f2bf(a[5] * scale) << 16);
    wv.w = f2bf(a[6] * scale) | (f2bf(a[7] * scale) << 16);
    *(uint4*)&meanL[w][node * 72 + g * 8] = wv;
  }
  __syncthreads();  // W + all mean tiles staged

  // ---- phase B: MFMA ----
  int c = lane & 15;   // A row / C-D col
  int kb = lane >> 4;  // k-block of 8
  bf16x8 bf[4][NT];
#pragma unroll
  for (int s = 0; s < 4; ++s)
#pragma unroll
    for (int nt = 0; nt < NT; ++nt)
      bf[s][nt] = *(const bf16x8*)&Wlds[(((s * NT + nt) * 16 + c) * 4 + kb) * 8];

  bf16x8 af[4];
  af[0] = *(const bf16x8*)&meanL[w][c * 72 + kb * 8];        // mean, k 0..31
  af[1] = *(const bf16x8*)&meanL[w][c * 72 + 32 + kb * 8];   // mean, k 32..63
  int row = r0 + c;
  if (row >= n) row = n - 1;  // clamp loads; stores guarded
  size_t rb = (size_t)row * 64 + kb * 8;
  af[2] = *(const bf16x8*)(h + rb);        // own row, k 0..31
  af[3] = *(const bf16x8*)(h + rb + 32);   // own row, k 32..63

  f32x4 acc[NT];
#pragma unroll
  for (int nt = 0; nt < NT; ++nt) acc[nt] = (f32x4){0.f, 0.f, 0.f, 0.f};
#pragma unroll
  for (int s = 0; s < 4; ++s)
#pragma unroll
    for (int nt = 0; nt < NT; ++nt)
      acc[nt] = __builtin_amdgcn_mfma_f32_16x16x32_bf16(af[s], bf[s][nt], acc[nt], 0, 0, 0);

  int rbase = r0 + kb * 4;
  if (ACT == ACT_RELU) {
    unsigned short* out = (unsigned short*)outv;
#pragma unroll
    for (int nt = 0; nt < NT; ++nt) {
      float bval = bias[nt * 16 + c];
#pragma unroll
      for (int r = 0; r < 4; ++r) {
        int R = rbase + r;
        if (R < n) {
          float v = fmaxf(acc[nt][r] + bval, 0.f);
          out[(size_t)R * DOUT + nt * 16 + c] = (unsigned short)f2bf(v);
        }
      }
    }
  } else {
    float* out = (float*)outv;
    float bv[NT];
#pragma unroll
    for (int nt = 0; nt < NT; ++nt) bv[nt] = ((nt * 16 + c) < DOUT) ? bias[nt * 16 + c] : 0.f;
#pragma unroll
    for (int r = 0; r < 4; ++r) {
      int R = rbase + r;
      float v[NT];
      float m = -INFINITY;
#pragma unroll
      for (int nt = 0; nt < NT; ++nt) {
        bool valid = (nt * 16 + c) < DOUT;
        v[nt] = valid ? (acc[nt][r] + bv[nt]) : -INFINITY;
        m = fmaxf(m, v[nt]);
      }
#pragma unroll
      for (int off = 1; off < 16; off <<= 1) m = fmaxf(m, __shfl_xor(m, off));
      float es = 0.f;
#pragma unroll
      for (int nt = 0; nt < NT; ++nt)
        if ((nt * 16 + c) < DOUT) es += expf(v[nt] - m);
#pragma unroll
      for (int off = 1; off < 16; off <<= 1) es += __shfl_xor(es, off);
      float lse = logf(es);
      if (R < n) {
#pragma unroll
        for (int nt = 0; nt < NT; ++nt)
          if ((nt * 16 + c) < DOUT) out[(size_t)R * DOUT + nt * 16 + c] = v[nt] - m - lse;
      }
    }
  }
}

extern "C" void kernel_launch(void* const* d_in, const int* in_sizes, int n_in,
                              void* d_out, int out_size, void* d_ws, size_t ws_size,
                              hipStream_t stream) {
  const float* x   = (const float*)d_in[0];
  const int*   ei  = (const int*)d_in[1];
  const float* Wl0 = (const float*)d_in[2];
  const float* bl0 = (const float*)d_in[3];
  const float* Wr0 = (const float*)d_in[4];
  const float* Wl1 = (const float*)d_in[5];
  const float* bl1 = (const float*)d_in[6];
  const float* Wr1 = (const float*)d_in[7];
  const float* Wl2 = (const float*)d_in[8];
  const float* bl2 = (const float*)d_in[9];
  const float* Wr2 = (const float*)d_in[10];
  float* out = (float*)d_out;

  int N = in_sizes[0] / 64;
  int E = in_sizes[1] / 2;
  int M = N + 1;
  int NB = (N + 255) >> BSH;  // 391 for N=100000
  const int* src = ei;
  const int* dst = ei + E;

  char* p = (char*)d_ws;
  auto alloc = [&](size_t bytes) {
    char* r = p;
    p += (bytes + 255) & ~(size_t)255;
    return r;
  };
  int* cnt      = (int*)alloc((size_t)M * 4);
  int* row_ptr  = (int*)alloc((size_t)M * 4);
  int* cursor   = (int*)alloc((size_t)M * 4);
  int* bsum     = (int*)alloc(256 * 4);
  int* boff     = (int*)alloc(256 * 4);
  int* bk_cnt   = (int*)alloc((MAXNB + 1) * 4);
  int* bk_base  = (int*)alloc((MAXNB + 1) * 4);
  int* bk_cur   = (int*)alloc((MAXNB + 1) * 4);
  int* edge_src = (int*)alloc((size_t)E * 4);
  // R1: int2 tmp during CSR build, then xb (bf16 x)
  size_t szR1 = (size_t)E * 8 > (size_t)N * 128 ? (size_t)E * 8 : (size_t)N * 128;
  char* R1            = alloc(szR1);
  unsigned short* hbA = (unsigned short*)alloc((size_t)N * 128);  // hidden (bf16)
  unsigned short* hbB = (unsigned short*)alloc((size_t)N * 128);  // hidden (bf16)
  if ((size_t)(p - (char*)d_ws) > ws_size) return;  // ws too small: fail loudly

  bool bucketed = (NB <= MAXNB);
  int eb4 = (E + 4095) / 4096;

  if (bucketed) {
    k_zero<<<(MAXNB + 256) / 256, 256, 0, stream>>>(bk_cnt, MAXNB + 1);
    k_histB<<<eb4, 256, 0, stream>>>(dst, bk_cnt, E, NB);
    k_bscan<<<1, MAXNB, 0, stream>>>(bk_cnt, bk_base, bk_cur, NB);
    k_partition<<<eb4, 256, 0, stream>>>(src, dst, bk_cur, (int2*)R1, E, NB);
    k_bmake<<<NB, 256, 0, stream>>>((const int2*)R1, bk_base, row_ptr, edge_src, N, E, NB);
  } else {
    k_zero<<<(M + 255) / 256, 256, 0, stream>>>(cnt, M);
    k_hist<<<(E + 255) / 256, 256, 0, stream>>>(dst, cnt, E);
    int nb = (M + 2047) / 2048;
    k_scan_part<<<nb, 256, 0, stream>>>(cnt, bsum, M);
    k_scan_mid<<<1, 64, 0, stream>>>(bsum, boff, nb);
    k_scan_final<<<nb, 256, 0, stream>>>(cnt, boff, row_ptr, cursor, M);
    k_fill<<<(E + 255) / 256, 256, 0, stream>>>(src, dst, cursor, edge_src, E);
  }

  unsigned short* xb = (unsigned short*)R1;  // reuses tmp region (dead after k_bmake)

  int cb = (N * 64 / 8 + 255) / 256;
  int gb = (N + 63) / 64;

  k_cast<<<cb, 256, 0, stream>>>(x, xb, N * 64);
  // layer 0: hbA = relu([mean_agg(xb), xb] @ [Wl0; Wr0] + bl0)
  k_layer<64, ACT_RELU><<<gb, 256, 0, stream>>>(xb, row_ptr, edge_src, Wl0, Wr0, bl0, hbA, N);
  // layer 1: hbB = relu([mean_agg(hbA), hbA] @ [Wl1; Wr1] + bl1)
  k_layer<64, ACT_RELU><<<gb, 256, 0, stream>>>(hbA, row_ptr, edge_src, Wl1, Wr1, bl1, hbB, N);
  // layer 2: out = log_softmax([mean_agg(hbB), hbB] @ [Wl2; Wr2] + bl2)
  k_layer<40, ACT_LSM><<<gb, 256, 0, stream>>>(hbB, row_ptr, edge_src, Wl2, Wr2, bl2, out, N);
}